// Round 7
// baseline (318.229 us; speedup 1.0000x reference)
//
#include <hip/hip_runtime.h>
#include <math.h>

// Problem constants
#define BATCH 2
#define NCAM 6
#define DIM 256
#define HEADS 8
#define DH 32
#define HW 2500          // 50*50
#define KP 625           // 25*25 pooled keys per cam
#define NDIM (NCAM*DIM)  // 1536

// scale/sqrt(dh) folded with log2(e) into the qf GEMM epilogue:
// 1.4426950408889634 / sqrt(32) = 0.25503488494404
#define SCALE_LOG2E 0.25503488494404f

typedef __attribute__((ext_vector_type(8))) short short8;
typedef __attribute__((ext_vector_type(4))) float f32x4;

__device__ __forceinline__ short f2bf(float f) {
    union { float f; unsigned u; } v; v.f = f;
    unsigned r = v.u + 0x7fffu + ((v.u >> 16) & 1u);   // round-to-nearest-even
    return (short)(r >> 16);
}
__device__ __forceinline__ float bf2f(short h) {
    union { unsigned u; float f; } v; v.u = ((unsigned)(unsigned short)h) << 16;
    return v.f;
}
// 2^x via the HW base-2 exp instruction
__device__ __forceinline__ float exp2_hw(float x) {
    return __builtin_amdgcn_exp2f(x);
}

// ---------------------------------------------------------------------------
// prep_all: ALL one-time data conversion in ONE launch (as R7).
// ---------------------------------------------------------------------------
struct WJ { const float* src; short* dst; int K, N; };
struct WArgs { WJ j[7]; };

__global__ __launch_bounds__(256) void prep_all(
    const float* __restrict__ q, const float* __restrict__ k,
    const float* __restrict__ v, short* __restrict__ qbf,
    short* __restrict__ kpbf, short* __restrict__ vpbf, WArgs wa)
{
    __shared__ float t[32][33];
    const int tx = threadIdx.x & 31, ty = threadIdx.x >> 5;   // ty 0..7
    int i = blockIdx.x;
    if (i < 7584) {
        int slab = i / 632, rem = i % 632;
        int hwB = (rem % 79) * 32, dB = (rem / 79) * 32;
        const float* src = q + (size_t)slab * 640000;
#pragma unroll
        for (int ii = 0; ii < 32; ii += 8) {
            int hw = hwB + tx;
            t[ty + ii][tx] = (hw < HW) ? src[(size_t)(dB + ty + ii) * HW + hw] : 0.f;
        }
        __syncthreads();
#pragma unroll
        for (int ii = 0; ii < 32; ii += 8) {
            int hw = hwB + ty + ii;
            if (hw < HW)
                qbf[((size_t)slab * HW + hw) * DIM + dB + tx] = f2bf(t[tx][ty + ii]);
        }
    } else if (i < 11424) {
        int i2 = i - 7584;
        const float* base; short* dst;
        if (i2 < 1920) { base = k; dst = kpbf; }
        else           { base = v; dst = vpbf; i2 -= 1920; }
        int slab = i2 / 160, rem = i2 % 160;
        int kpB = (rem % 20) * 32, dB = (rem / 20) * 32;
        const float* src = base + (size_t)slab * 640000;
        dst += (size_t)slab * (KP * DIM);
#pragma unroll
        for (int ii = 0; ii < 32; ii += 8) {
            int kp = kpB + tx;
            float val = 0.f;
            if (kp < KP) {
                int r2 = (kp / 25) * 2, c2 = (kp % 25) * 2;
                const float* p0 = src + (size_t)(dB + ty + ii) * HW + r2 * 50 + c2;
                val = 0.25f * (p0[0] + p0[1] + p0[50] + p0[51]);
            }
            t[ty + ii][tx] = val;
        }
        __syncthreads();
#pragma unroll
        for (int ii = 0; ii < 32; ii += 8) {
            int kp = kpB + ty + ii;
            if (kp < KP)
                dst[(size_t)kp * DIM + dB + tx] = f2bf(t[tx][ty + ii]);
        }
    } else {
        int wi = i - 11424;
        WJ jb = wa.j[0];
        for (int jj = 0; jj < 7; jj++) {
            jb = wa.j[jj];
            int cnt = (jb.K >> 5) * (jb.N >> 5);
            if (wi < cnt) break;
            wi -= cnt;
        }
        int tn = jb.N >> 5;
        int nB = (wi % tn) * 32, kB = (wi / tn) * 32;
#pragma unroll
        for (int ii = 0; ii < 32; ii += 8)
            t[ty + ii][tx] = jb.src[(size_t)(kB + ty + ii) * jb.N + nB + tx];
        __syncthreads();
#pragma unroll
        for (int ii = 0; ii < 32; ii += 8)
            jb.dst[(size_t)(nB + ty + ii) * jb.K + kB + tx] = f2bf(t[tx][ty + ii]);
    }
}

// ---------------------------------------------------------------------------
// Batched input GEMMs, flat 1D grid (no dead blocks, no swizzle: HW
// round-robin spreads the long add_q blocks across all XCDs), add_q
// split-K (2x768).  LDS double-buffer, ONE barrier per K-tile, write-early
// staging: per tile t -> stage regs(t+1) into buf^1 (vmcnt window = full
// previous iteration), issue loads(t+2), ds_read buf + MFMA, barrier.
// ---------------------------------------------------------------------------
struct GJob { const short* A; const short* Bt; const float* bias;
              short* Cb; float* Cf; int M, Ks, Kl, kOff, mode; float smul; };
struct GArgs { GJob j[5]; int base[6]; };

__global__ __launch_bounds__(256) void gemm_in(GArgs ga) {
    int bid = blockIdx.x;
    int jj = 0;
    while (bid >= ga.base[jj + 1]) jj++;
    GJob jb = ga.j[jj];
    const int local = bid - ga.base[jj];

    __shared__ short As[2][128 * 32];
    __shared__ short Bs[2][64 * 32];

    const int tid  = threadIdx.x;
    const int nB   = (local & 3) * 64;
    const int rB   = (local >> 2) * 128;
    const int w    = tid >> 6;
    const int lane = tid & 63;
    const int l15  = lane & 15;
    const int quad = lane >> 4;
    const int M = jb.M, Ks = jb.Ks, kOff = jb.kOff;
    const int nT = jb.Kl >> 5;

    f32x4 acc[2][4];
#pragma unroll
    for (int i = 0; i < 2; i++)
#pragma unroll
        for (int jt = 0; jt < 4; jt++) acc[i][jt] = (f32x4){0.f, 0.f, 0.f, 0.f};

    const int ra = tid >> 1, k0 = (tid & 1) * 16;   // A staging
    const int rga = rB + ra;
    const int bb = rga / 2500, hwp = rga % 2500;    // mode 1 row decode
    const int nb_ = tid >> 2, gkb = tid & 3;        // B staging
    const int g0 = k0 >> 3;

    short8 pa0 = {0,0,0,0,0,0,0,0}, pa1 = pa0, pb = pa0;

#define GLOADT(t) do {                                                        \
        int kk = kOff + (t) * 32 + k0;                                        \
        if (rga < M) {                                                        \
            const short* p;                                                   \
            if (jb.mode) {                                                    \
                int cam = kk >> 8, c = kk & 255;                              \
                p = &jb.A[(((size_t)(bb * 6 + cam)) * HW + hwp) * DIM + c];   \
            } else {                                                          \
                p = &jb.A[(size_t)rga * Ks + kk];                             \
            }                                                                 \
            pa0 = *(const short8*)p; pa1 = *(const short8*)(p + 8);           \
        }                                                                     \
        pb = *(const short8*)&jb.Bt[(size_t)(nB + nb_) * Ks                   \
                                    + kOff + (t) * 32 + gkb * 8];             \
    } while (0)

#define STAGET(bf) do {                                                       \
        *(short8*)&As[bf][ra * 32 + ((g0 ^ (ra & 3)) << 3)]       = pa0;      \
        *(short8*)&As[bf][ra * 32 + (((g0 + 1) ^ (ra & 3)) << 3)] = pa1;      \
        *(short8*)&Bs[bf][nb_ * 32 + ((gkb ^ (nb_ & 3)) << 3)]    = pb;       \
    } while (0)

    // prologue: tile 0 -> buf0; issue tile 1 loads
    GLOADT(0);
    STAGET(0);
    if (nT > 1) GLOADT(1);
    __syncthreads();

    int cur = 0;
    for (int t = 0; t < nT; t++) {
        // stage tile t+1 (regs, loaded last iter) into the other buffer.
        // Safe: reads of buf[cur^1] (tile t-1) completed before the barrier
        // that ended epoch t-1.
        if (t + 1 < nT) STAGET(cur ^ 1);
        // issue loads for tile t+2 (consumed at stage in epoch t+1)
        if (t + 2 < nT) GLOADT(t + 2);
        // compute tile t from buf[cur]
        short8 af[2], bfr[4];
#pragma unroll
        for (int i = 0; i < 2; i++) {
            int m = w * 32 + i * 16 + l15;
            af[i] = *(const short8*)&As[cur][m * 32 + ((quad ^ (m & 3)) << 3)];
        }
#pragma unroll
        for (int jt = 0; jt < 4; jt++) {
            int n = jt * 16 + l15;
            bfr[jt] = *(const short8*)&Bs[cur][n * 32 + ((quad ^ (n & 3)) << 3)];
        }
#pragma unroll
        for (int i = 0; i < 2; i++)
#pragma unroll
            for (int jt = 0; jt < 4; jt++)
                acc[i][jt] = __builtin_amdgcn_mfma_f32_16x16x32_bf16(
                    af[i], bfr[jt], acc[i][jt], 0, 0, 0);
        if (t + 1 < nT) { __syncthreads(); cur ^= 1; }
    }
#undef GLOADT
#undef STAGET

#pragma unroll
    for (int i = 0; i < 2; i++) {
        int rbase = rB + w * 32 + i * 16 + quad * 4;
#pragma unroll
        for (int jt = 0; jt < 4; jt++) {
            int col = nB + jt * 16 + l15;
            float bcol = jb.bias ? jb.bias[col] : 0.f;
#pragma unroll
            for (int reg = 0; reg < 4; reg++) {
                int rr = rbase + reg;
                if (rr < M) {
                    float vv = (acc[i][jt][reg] + bcol) * jb.smul;
                    if (jb.Cb) jb.Cb[(size_t)rr * 256 + col] = f2bf(vv);
                    else       jb.Cf[(size_t)rr * 256 + col] = vv;
                }
            }
        }
    }
}

// ---------------------------------------------------------------------------
// Tail GEMM, BM=128 (RT=2) + register-prefetch dbuf.
// EPI 0: bias; 1: bias+GELU; 2: bias+res(+res2).  WF32: fp32 C; WBF: bf16 C2.
// ---------------------------------------------------------------------------
template<int EPI, int WF32, int WBF>
__global__ __launch_bounds__(256) void mgemm_bf(
    const short* __restrict__ A, const short* __restrict__ Bt,
    const float* __restrict__ bias, const float* __restrict__ res,
    const float* __restrict__ res2,
    float* __restrict__ C, short* __restrict__ C2, int M, int N, int K)
{
    __shared__ short As[128 * 32];
    __shared__ short Bs[64 * 32];

    const int tid  = threadIdx.x;
    const int nB   = blockIdx.x * 64;
    const int rB   = blockIdx.y * 128;
    const int w    = tid >> 6;
    const int lane = tid & 63;
    const int l15  = lane & 15;
    const int quad = lane >> 4;

    f32x4 acc[2][4];
#pragma unroll
    for (int i = 0; i < 2; i++)
#pragma unroll
        for (int jt = 0; jt < 4; jt++) acc[i][jt] = (f32x4){0.f, 0.f, 0.f, 0.f};

    const int ra = tid >> 1, k0 = (tid & 1) * 16;
    const int rga = rB + ra;
    const int nb_ = tid >> 2, gkb = tid & 3;

    short8 pa0 = {0,0,0,0,0,0,0,0}, pa1 = pa0, pb = pa0;
    if (rga < M) {
        const short* p = &A[(size_t)rga * K + k0];
        pa0 = *(const short8*)p; pa1 = *(const short8*)(p + 8);
    }
    pb = *(const short8*)&Bt[(size_t)(nB + nb_) * K + gkb * 8];

    for (int kB = 0; kB < K; kB += 32) {
        __syncthreads();
        {
            int g0 = k0 >> 3;
            *(short8*)&As[ra * 32 + ((g0 ^ (ra & 3)) << 3)]       = pa0;
            *(short8*)&As[ra * 32 + (((g0 + 1) ^ (ra & 3)) << 3)] = pa1;
            *(short8*)&Bs[nb_ * 32 + ((gkb ^ (nb_ & 3)) << 3)]    = pb;
        }
        __syncthreads();
        int kN = kB + 32;
        if (kN < K) {
            if (rga < M) {
                const short* p = &A[(size_t)rga * K + kN + k0];
                pa0 = *(const short8*)p; pa1 = *(const short8*)(p + 8);
            }
            pb = *(const short8*)&Bt[(size_t)(nB + nb_) * K + kN + gkb * 8];
        }
        short8 af[2], bfr[4];
#pragma unroll
        for (int i = 0; i < 2; i++) {
            int m = w * 32 + i * 16 + l15;
            af[i] = *(const short8*)&As[m * 32 + ((quad ^ (m & 3)) << 3)];
        }
#pragma unroll
        for (int jt = 0; jt < 4; jt++) {
            int n = jt * 16 + l15;
            bfr[jt] = *(const short8*)&Bs[n * 32 + ((quad ^ (n & 3)) << 3)];
        }
#pragma unroll
        for (int i = 0; i < 2; i++)
#pragma unroll
            for (int jt = 0; jt < 4; jt++)
                acc[i][jt] = __builtin_amdgcn_mfma_f32_16x16x32_bf16(
                    af[i], bfr[jt], acc[i][jt], 0, 0, 0);
    }
#pragma unroll
    for (int i = 0; i < 2; i++) {
        int rbase = rB + w * 32 + i * 16 + quad * 4;
#pragma unroll
        for (int jt = 0; jt < 4; jt++) {
            int col = nB + jt * 16 + l15;
            float bcol = bias[col];
#pragma unroll
            for (int reg = 0; reg < 4; reg++) {
                int rr = rbase + reg;
                if (rr < M) {
                    float vv = acc[i][jt][reg] + bcol;
                    if (EPI == 1) vv = 0.5f * vv * (1.f + erff(vv * 0.70710678118654752f));
                    if (EPI == 2) {
                        vv += res[(size_t)rr * N + col];
                        if (res2) vv += res2[(size_t)rr * N + col];
                    }
                    if (WF32) C[(size_t)rr * N + col] = vv;
                    if (WBF)  C2[(size_t)rr * N + col] = f2bf(vv);
                }
            }
        }
    }
}

// ---------------------------------------------------------------------------
// MFMA attention, R7: P in registers + Z on the MFMA pipe.
// Swapped QK^T over kappa-permuted K rows gives lane (quad,l15) the PV
// A-fragments directly (see R2 notes).  Z is now computed by an extra MFMA
// per ks against an all-ones B-fragment (any B-layout valid since B==1):
// zacc C-layout rows = q (quad*4+reg), all 16 cols identical.  This deletes
// 16 VALU adds + 2 shuffles per chunk and makes Z the sum of the SAME
// rounded-bf16 P used in the PV numerator.
// ---------------------------------------------------------------------------
#define TQA 64
#define CH 64
#define VSTR 72

__global__ __launch_bounds__(256) void attn_mfma(
    const short* __restrict__ qf, const short* __restrict__ kf,
    const short* __restrict__ vf, short* __restrict__ attn_out,
    float* __restrict__ Zp)
{
    const int qt  = blockIdx.x;
    const int bm  = blockIdx.y;
    const int cam = blockIdx.z;
    const int b = bm >> 3, m = bm & 7;
    const int q0 = qt * TQA;
    const int tid = threadIdx.x;
    const int w = tid >> 6, lane = tid & 63;
    const int l15 = lane & 15, quad = lane >> 4;

    __shared__ __align__(16) short Ks[CH][DH];
    __shared__ __align__(16) short Vt[DH][VSTR];

    const size_t slab = (size_t)(b * 6 + cam);

    int qrow = q0 + w * 16 + l15;
    int qcl  = qrow < HW ? qrow : HW - 1;
    const short8 aq = *(const short8*)&qf[(slab * HW + qcl) * DIM + m * DH + quad * 8];

    const short* kb = kf + slab * KP * DIM + m * DH;
    const short* vb = vf + slab * KP * DIM + m * DH;

    f32x4 oacc[2];
    oacc[0] = (f32x4){0.f, 0.f, 0.f, 0.f};
    oacc[1] = (f32x4){0.f, 0.f, 0.f, 0.f};
    f32x4 zacc = (f32x4){0.f, 0.f, 0.f, 0.f};
    const short one_bf = (short)0x3F80;                 // bf16 1.0
    const short8 ones8 = {one_bf, one_bf, one_bf, one_bf,
                          one_bf, one_bf, one_bf, one_bf};

    // K staging: one b128 per thread, kappa-permuted destination row
    const int kl = tid >> 2, d8 = (tid & 3) * 8;
    const int jtw  = ((kl >> 5) & 1) | (((kl >> 2) & 1) << 1);
    const int rw   = (((kl >> 3) & 3) << 2) | (kl & 3);
    const int krow = jtw * 16 + rw;
    // V pair staging: two adjacent keys, 4 dh each -> 4 ds_write_b32
    const int kp2 = tid >> 3, dv = (tid & 7) * 4;
    const int vcol2 = (((kp2 >> 2) ^ (dv >> 3)) << 3) | ((2 * kp2) & 7);

    for (int c0 = 0; c0 < KP; c0 += CH) {
        __syncthreads();
        {
            int key = c0 + kl;
            short8 kv8 = {0, 0, 0, 0, 0, 0, 0, 0};
            if (key < KP) kv8 = *(const short8*)&kb[(size_t)key * DIM + d8];
            *(short8*)&Ks[krow][d8] = kv8;

            int k0v = c0 + 2 * kp2;
            uint2 a0 = {0u, 0u}, a1 = {0u, 0u};
            if (k0v < KP)     a0 = *(const uint2*)&vb[(size_t)k0v * DIM + dv];
            if (k0v + 1 < KP) a1 = *(const uint2*)&vb[(size_t)(k0v + 1) * DIM + dv];
            // interleave keys: (v0[t] | v1[t]<<16) via v_perm_b32
            *(unsigned*)&Vt[dv + 0][vcol2] = __builtin_amdgcn_perm(a1.x, a0.x, 0x05040100u);
            *(unsigned*)&Vt[dv + 1][vcol2] = __builtin_amdgcn_perm(a1.x, a0.x, 0x07060302u);
            *(unsigned*)&Vt[dv + 2][vcol2] = __builtin_amdgcn_perm(a1.y, a0.y, 0x05040100u);
            *(unsigned*)&Vt[dv + 3][vcol2] = __builtin_amdgcn_perm(a1.y, a0.y, 0x07060302u);
        }
        __syncthreads();
        // swapped QK^T over kappa-permuted K rows
        f32x4 sfragT[4];
#pragma unroll
        for (int jt = 0; jt < 4; jt++) {
            short8 bk8 = *(const short8*)&Ks[jt * 16 + l15][quad * 8];
            sfragT[jt] = __builtin_amdgcn_mfma_f32_16x16x32_bf16(
                bk8, aq, (f32x4){0.f, 0.f, 0.f, 0.f}, 0, 0, 0);
        }
        // softmax numerator -> in-register PV A-fragments
        union PA { unsigned u[4]; short8 s8; } pa[2];
        if (c0 + CH <= KP) {   // full chunk (0..8): no key masking
#pragma unroll
            for (int jt = 0; jt < 4; jt++) {
                float e0 = exp2_hw(sfragT[jt][0]);
                float e1 = exp2_hw(sfragT[jt][1]);
                float e2 = exp2_hw(sfragT[jt][2]);
                float e3 = exp2_hw(sfragT[jt][3]);
                asm("v_cvt_pk_bf16_f32 %0, %1, %2"
                    : "=v"(pa[jt & 1].u[(jt >> 1) * 2]) : "v"(e0), "v"(e1));
                asm("v_cvt_pk_bf16_f32 %0, %1, %2"
                    : "=v"(pa[jt & 1].u[(jt >> 1) * 2 + 1]) : "v"(e2), "v"(e3));
            }
        } else {               // tail chunk: mask keys >= KP
            int kq8 = c0 + quad * 8;
#pragma unroll
            for (int jt = 0; jt < 4; jt++) {
                int kb0 = kq8 + (jt & 1) * 32 + ((jt >> 1) << 2);
                float e0 = (kb0 + 0 < KP) ? exp2_hw(sfragT[jt][0]) : 0.f;
                float e1 = (kb0 + 1 < KP) ? exp2_hw(sfragT[jt][1]) : 0.f;
                float e2 = (kb0 + 2 < KP) ? exp2_hw(sfragT[jt][2]) : 0.f;
                float e3 = (kb0 + 3 < KP) ? exp2_hw(sfragT[jt][3]) : 0.f;
                asm("v_cvt_pk_bf16_f32 %0, %1, %2"
                    : "=v"(pa[jt & 1].u[(jt >> 1) * 2]) : "v"(e0), "v"(e1));
                asm("v_cvt_pk_bf16_f32 %0, %1, %2"
                    : "=v"(pa[jt & 1].u[(jt >> 1) * 2 + 1]) : "v"(e2), "v"(e3));
            }
        }
        // PV: A-fragment direct from registers; Vt reads unchanged.
        // Z rides the MFMA pipe via the ones-fragment.
#pragma unroll
        for (int ks = 0; ks < 2; ks++) {
#pragma unroll
            for (int nt = 0; nt < 2; nt++) {
                int dhn = nt * 16 + l15;
                int pgrp = ((ks * 4 + quad) ^ (dhn >> 3));
                short8 bv8 = *(const short8*)&Vt[dhn][pgrp << 3];
                oacc[nt] = __builtin_amdgcn_mfma_f32_16x16x32_bf16(
                    pa[ks].s8, bv8, oacc[nt], 0, 0, 0);
            }
            zacc = __builtin_amdgcn_mfma_f32_16x16x32_bf16(
                pa[ks].s8, ones8, zacc, 0, 0, 0);
        }
    }
    // zacc rows = q (quad*4+reg); all 16 cols identical -> write from l15==0
    if (l15 == 0) {
#pragma unroll
        for (int reg = 0; reg < 4; reg++) {
            int q = q0 + w * 16 + quad * 4 + reg;
            if (q < HW) Zp[((size_t)bm * 6 + cam) * HW + q] = zacc[reg];
        }
    }
#pragma unroll
    for (int reg = 0; reg < 4; reg++) {
        int q = q0 + w * 16 + quad * 4 + reg;
        if (q < HW) {
            size_t rowb = ((size_t)b * HW + q) * NDIM + cam * DIM + m * DH;
            attn_out[rowb + l15]      = f2bf(oacc[0][reg]);
            attn_out[rowb + 16 + l15] = f2bf(oacc[1][reg]);
        }
    }
}

// ---------------------------------------------------------------------------
// LayerNorm over 1536 (bf16 in) + fused joint-softmax normalization -> bf16.
// ---------------------------------------------------------------------------
__global__ __launch_bounds__(256) void ln_pre_kernel(
    const short* __restrict__ xin, short* __restrict__ lnbf,
    const float* __restrict__ Zp,
    const float* __restrict__ g, const float* __restrict__ bt)
{
    const int row = blockIdx.x;
    const int tid = threadIdx.x;
    const int b = row / 2500, q = row % 2500;
    __shared__ float zinv[8];
    if (tid < 8) {
        float z = 0.f;
#pragma unroll
        for (int cam = 0; cam < 6; cam++)
            z += Zp[((size_t)(b * 8 + tid) * 6 + cam) * HW + q];
        zinv[tid] = 1.f / z;
    }
    __syncthreads();
    const short* p = xin + (size_t)row * NDIM;
    float v[6];
    float s = 0.f, ss = 0.f;
#pragma unroll
    for (int i = 0; i < 6; i++) {
        int c = tid + i * 256;
        v[i] = bf2f(p[c]) * zinv[(c >> 5) & 7];
        s += v[i]; ss += v[i] * v[i];
    }
    __shared__ float rs[4], rss[4];
    int lane = tid & 63, wid = tid >> 6;
#pragma unroll
    for (int o = 32; o > 0; o >>= 1) { s += __shfl_down(s, o); ss += __shfl_down(ss, o); }
    if (lane == 0) { rs[wid] = s; rss[wid] = ss; }
    __syncthreads();
    s = rs[0] + rs[1] + rs[2] + rs[3];
    ss = rss[0] + rss[1] + rss[2] + rss[3];
    float mu = s * (1.f / NDIM);
    float var = ss * (1.f / NDIM) - mu * mu;
    float inv = rsqrtf(var + 1e-5f);
#pragma unroll
    for (int i = 0; i < 6; i++) {
        int c = tid + i * 256;
        lnbf[(size_t)row * NDIM + c] = f2bf((v[i] - mu) * inv * g[c] + bt[c]);
    }
}

// ---------------------------------------------------------------------------
// final2 (as R7): coalesced transpose store.
// ---------------------------------------------------------------------------
__global__ __launch_bounds__(256) void final_kernel2(
    const float* __restrict__ x, const float* __restrict__ y2,
    const float* __restrict__ g, const float* __restrict__ bt,
    float* __restrict__ out)
{
    __shared__ float T[256][33];
    __shared__ float ps[32][8], pss[32][8];
    __shared__ float mu_s[32], inv_s[32];
    const int tid = threadIdx.x;
    const int rl = tid & 31, seg = tid >> 5;
    const int r0 = blockIdx.x * 32;
    const int row = r0 + rl;
    const bool ok = row < 5000;

    float4 yv[8];
    float s = 0.f, ss = 0.f;
    if (ok) {
        const float4* yp = (const float4*)(y2 + (size_t)row * DIM + seg * 32);
#pragma unroll
        for (int j = 0; j < 8; j++) {
            yv[j] = yp[j];
            s += yv[j].x + yv[j].y + yv[j].z + yv[j].w;
            ss += yv[j].x * yv[j].x + yv[j].y * yv[j].y
                + yv[j].z * yv[j].z + yv[j].w * yv[j].w;
        }
    } else {
#pragma unroll
        for (int j = 0; j < 8; j++) yv[j] = (float4){0, 0, 0, 0};
    }
    ps[rl][seg] = s; pss[rl][seg] = ss;
    __syncthreads();
    if (tid < 32) {
        float a = 0.f, b2 = 0.f;
#pragma unroll
        for (int j = 0; j < 8; j++) { a += ps[tid][j]; b2 += pss[tid][j]; }
        float mu = a * (1.f / DIM);
        float var = b2 * (1.f / DIM) - mu * mu;
        mu_s[tid] = mu;
        inv_s[tid] = rsqrtf(var + 1e-5f);
    }
    __syncthreads();
    if (ok) {
        float mu = mu_s[rl], inv = inv_s[rl];
        const float4* xp = (const float4*)(x + (size_t)row * DIM + seg * 32);
#pragma unroll
        for (int j = 0; j < 8; j++) {
            float4 xv = xp[j];
            int c = seg * 32 + j * 4;
            T[c + 0][rl] = xv.x + (yv[j].x - mu) * inv * g[c + 0] + bt[c + 0];
            T[c + 1][rl] = xv.y + (yv[j].y - mu) * inv * g[c + 1] + bt[c + 1];
            T[c + 2][rl] = xv.z + (yv[j].z - mu) * inv * g[c + 2] + bt[c + 2];
            T[c + 3][rl] = xv.w + (yv[j].w - mu) * inv * g[c + 3] + bt[c + 3];
        }
    }
    __syncthreads();
    const int w = tid >> 6, lane = tid & 63;
    const int hl = lane & 31, ch = lane >> 5;
    const int rr = r0 + hl;
    if (rr < 5000) {
        int b = rr / 2500, hw = rr % 2500;
        size_t obase = (size_t)b * 640000 + hw;
#pragma unroll
        for (int it = 0; it < 32; it++) {
            int c = it * 8 + w * 2 + ch;
            out[obase + (size_t)c * 2500] = T[c][hl];
        }
    }
}

// ---------------------------------------------------------------------------
extern "C" void kernel_launch(void* const* d_in, const int* in_sizes, int n_in,
                              void* d_out, int out_size, void* d_ws, size_t ws_size,
                              hipStream_t stream)
{
    const float* q     = (const float*)d_in[0];
    const float* k     = (const float*)d_in[1];
    const float* v     = (const float*)d_in[2];
    const float* Wq    = (const float*)d_in[3];
    const float* bq    = (const float*)d_in[4];
    const float* Wk    = (const float*)d_in[5];
    const float* bk    = (const float*)d_in[6];
    const float* Wv    = (const float*)d_in[7];
    const float* bv    = (const float*)d_in[8];
    const float* Wproj = (const float*)d_in[9];
    const float* bproj = (const float*)d_in[10];
    const float* Waddq = (const float*)d_in[11];
    const float* baddq = (const float*)d_in[12];
    const float* W1    = (const float*)d_in[13];
    const float* b1    = (const float*)d_in[14];
    const float* W2    = (const float*)d_in[15];
    const float* b2    = (const float*)d_in[16];
    const float* g_pre = (const float*)d_in[17];
    const float* b_pre = (const float*)d_in[18];
    const float* g_nrm = (const float*)d_in[19];
    const float* b_nrm = (const float*)d_in[20];
    float* out = (float*)d_out;

    // workspace layout (float-unit offsets)
    float* ws = (float*)d_ws;
    short* qf_a   = (short*)(ws);             // [0, 3.84M)
    short* lnbf   = (short*)(ws);             //   alias after attn
    short* qbf    = (short*)(ws + 3840000);   // [3.84M, 7.68M)
    short* kf_a   = (short*)(ws + 7680000);   // [7.68M, 8.64M)
    short* kpbf   = (short*)(ws + 8640000);   // [8.64M, 9.6M)
    short* vf_a   = (short*)(ws + 9600000);   // [9.6M, 10.56M)
    short* vpbf   = (short*)(ws + 10560000);  // [10.56M, 11.52M)
    float* add_q  = ws + 11520000;            // [11.52M, 12.8M)
    short* attn_o = (short*)(ws + 12800000);  // bf16: [12.8M, 16.64M)
    short* xbf    = (short*)(ws + 12800000);  //   alias: live only after ln_pre
    short* h1bf   = (short*)(ws + 13440000);  //   alias: [13.44M, 14.72M)
    float* add_q2 = ws + 16640000;            // [16.64M, 17.92M) split-K partial
    float* x      = ws + 20480000;            // [20.48M, 21.76M)
    float* Zp     = ws + 21760000;            // [21.76M, 22M)
    short* eW     = (short*)(ws + 22000000);
    short* Wq_t    = eW;
    short* Wk_t    = eW + 65536;
    short* Wv_t    = eW + 131072;
    short* Waddq_t = eW + 196608;
    short* lW     = (short*)(ws + 22295000);
    short* Wproj_t = lW;
    short* W1_t    = lW + 393216;
    short* W2_t    = lW + 524288;
    float* y2     = ws + 22625000;            // [22.62M, 23.9M)

    dim3 blk(256);

    // 1) all conversion work in one launch
    {
        WArgs wa;
        wa.j[0] = {Wq,    Wq_t,    256,  256};
        wa.j[1] = {Wk,    Wk_t,    256,  256};
        wa.j[2] = {Wv,    Wv_t,    256,  256};
        wa.j[3] = {Waddq, Waddq_t, 1536, 256};
        wa.j[4] = {Wproj, Wproj_t, 1536, 256};
        wa.j[5] = {W1,    W1_t,    256,  512};
        wa.j[6] = {W2,    W2_t,    512,  256};
        prep_all<<<dim3(12640), blk, 0, stream>>>(q, k, v, qbf, kpbf, vpbf, wa);
    }
    // 2) all input-side GEMMs, flat grid: long add_q blocks first (HW
    //    round-robin spreads them across XCDs) + split-K(2x768)
    //    qf job pre-scales by softmax scale * log2e (consumed only by attn)
    {
        GArgs ga;
        //          A     Bt       bias     Cb       Cf      M      Ks    Kl   kOff mode smul
        ga.j[0] = {qbf,  Waddq_t, baddq,   nullptr, add_q,  5000,  1536, 768, 0,   1, 1.0f};
        ga.j[1] = {qbf,  Waddq_t, nullptr, nullptr, add_q2, 5000,  1536, 768, 768, 1, 1.0f};
        ga.j[2] = {qbf,  Wq_t,    bq,      qf_a,    nullptr, 30000, 256, 256, 0,   0, SCALE_LOG2E};
        ga.j[3] = {kpbf, Wk_t,    bk,      kf_a,    nullptr, 7500,  256, 256, 0,   0, 1.0f};
        ga.j[4] = {vpbf, Wv_t,    bv,      vf_a,    nullptr, 7500,  256, 256, 0,   0, 1.0f};
        int cnt[5] = {160, 160, 940, 236, 236};   // 40*4, 40*4, 235*4, 59*4, 59*4
        ga.base[0] = 0;
        for (int i = 0; i < 5; i++) ga.base[i + 1] = ga.base[i] + cnt[i];
        gemm_in<<<dim3(ga.base[5]), blk, 0, stream>>>(ga);
    }
    // 3) attention (bf16 out, P in registers, Z on MFMA pipe)
    attn_mfma<<<dim3(40, 16, 6), blk, 0, stream>>>(qf_a, kf_a, vf_a, attn_o, Zp);
    // 4) LN(1536) + softmax-normalize -> bf16 (into dead qf_a region)
    ln_pre_kernel<<<dim3(5000), blk, 0, stream>>>(attn_o, lnbf, Zp, g_pre, b_pre);
    // 5) x = ln @ Wproj + bproj + add_q + add_q2  (fp32 x + bf16 xbf)
    mgemm_bf<2, 1, 1><<<dim3(4, 40), blk, 0, stream>>>(
        lnbf, Wproj_t, bproj, add_q, add_q2, x, xbf, 5000, 256, 1536);
    // 6) h1 = gelu(x @ W1 + b1) -> bf16
    mgemm_bf<1, 0, 1><<<dim3(8, 40), blk, 0, stream>>>(
        xbf, W1_t, b1, nullptr, nullptr, nullptr, h1bf, 5000, 512, 256);
    // 7) y2 = h1 @ W2 + b2 -> fp32
    mgemm_bf<0, 1, 0><<<dim3(4, 40), blk, 0, stream>>>(
        h1bf, W2_t, b2, nullptr, nullptr, y2, nullptr, 5000, 256, 512);
    // 8) out = transpose(x + LN256(y2)) — coalesced
    final_kernel2<<<dim3(157), blk, 0, stream>>>(x, y2, g_nrm, b_nrm, out);
}

// Round 10
// 316.149 us; speedup vs baseline: 1.0066x; 1.0066x over previous
//
#include <hip/hip_runtime.h>
#include <math.h>

// Problem constants
#define BATCH 2
#define NCAM 6
#define DIM 256
#define HEADS 8
#define DH 32
#define HW 2500          // 50*50
#define KP 625           // 25*25 pooled keys per cam
#define NDIM (NCAM*DIM)  // 1536

// scale/sqrt(dh) folded with log2(e) into the qf GEMM epilogue:
// 1.4426950408889634 / sqrt(32) = 0.25503488494404
#define SCALE_LOG2E 0.25503488494404f

typedef __attribute__((ext_vector_type(8))) short short8;
typedef __attribute__((ext_vector_type(4))) float f32x4;

__device__ __forceinline__ short f2bf(float f) {
    union { float f; unsigned u; } v; v.f = f;
    unsigned r = v.u + 0x7fffu + ((v.u >> 16) & 1u);   // round-to-nearest-even
    return (short)(r >> 16);
}
__device__ __forceinline__ float bf2f(short h) {
    union { unsigned u; float f; } v; v.u = ((unsigned)(unsigned short)h) << 16;
    return v.f;
}
// 2^x via the HW base-2 exp instruction
__device__ __forceinline__ float exp2_hw(float x) {
    return __builtin_amdgcn_exp2f(x);
}

// ---------------------------------------------------------------------------
// prep_all: ALL one-time data conversion in ONE launch (as R7).
// ---------------------------------------------------------------------------
struct WJ { const float* src; short* dst; int K, N; };
struct WArgs { WJ j[7]; };

__global__ __launch_bounds__(256) void prep_all(
    const float* __restrict__ q, const float* __restrict__ k,
    const float* __restrict__ v, short* __restrict__ qbf,
    short* __restrict__ kpbf, short* __restrict__ vpbf, WArgs wa)
{
    __shared__ float t[32][33];
    const int tx = threadIdx.x & 31, ty = threadIdx.x >> 5;   // ty 0..7
    int i = blockIdx.x;
    if (i < 7584) {
        int slab = i / 632, rem = i % 632;
        int hwB = (rem % 79) * 32, dB = (rem / 79) * 32;
        const float* src = q + (size_t)slab * 640000;
#pragma unroll
        for (int ii = 0; ii < 32; ii += 8) {
            int hw = hwB + tx;
            t[ty + ii][tx] = (hw < HW) ? src[(size_t)(dB + ty + ii) * HW + hw] : 0.f;
        }
        __syncthreads();
#pragma unroll
        for (int ii = 0; ii < 32; ii += 8) {
            int hw = hwB + ty + ii;
            if (hw < HW)
                qbf[((size_t)slab * HW + hw) * DIM + dB + tx] = f2bf(t[tx][ty + ii]);
        }
    } else if (i < 11424) {
        int i2 = i - 7584;
        const float* base; short* dst;
        if (i2 < 1920) { base = k; dst = kpbf; }
        else           { base = v; dst = vpbf; i2 -= 1920; }
        int slab = i2 / 160, rem = i2 % 160;
        int kpB = (rem % 20) * 32, dB = (rem / 20) * 32;
        const float* src = base + (size_t)slab * 640000;
        dst += (size_t)slab * (KP * DIM);
#pragma unroll
        for (int ii = 0; ii < 32; ii += 8) {
            int kp = kpB + tx;
            float val = 0.f;
            if (kp < KP) {
                int r2 = (kp / 25) * 2, c2 = (kp % 25) * 2;
                const float* p0 = src + (size_t)(dB + ty + ii) * HW + r2 * 50 + c2;
                val = 0.25f * (p0[0] + p0[1] + p0[50] + p0[51]);
            }
            t[ty + ii][tx] = val;
        }
        __syncthreads();
#pragma unroll
        for (int ii = 0; ii < 32; ii += 8) {
            int kp = kpB + ty + ii;
            if (kp < KP)
                dst[(size_t)kp * DIM + dB + tx] = f2bf(t[tx][ty + ii]);
        }
    } else {
        int wi = i - 11424;
        WJ jb = wa.j[0];
        for (int jj = 0; jj < 7; jj++) {
            jb = wa.j[jj];
            int cnt = (jb.K >> 5) * (jb.N >> 5);
            if (wi < cnt) break;
            wi -= cnt;
        }
        int tn = jb.N >> 5;
        int nB = (wi % tn) * 32, kB = (wi / tn) * 32;
#pragma unroll
        for (int ii = 0; ii < 32; ii += 8)
            t[ty + ii][tx] = jb.src[(size_t)(kB + ty + ii) * jb.N + nB + tx];
        __syncthreads();
#pragma unroll
        for (int ii = 0; ii < 32; ii += 8)
            jb.dst[(size_t)(nB + ty + ii) * jb.K + kB + tx] = f2bf(t[tx][ty + ii]);
    }
}

// ---------------------------------------------------------------------------
// Batched input GEMMs, flat 1D grid (no dead blocks, no swizzle: HW
// round-robin spreads the long add_q blocks across all XCDs), add_q
// split-K (2x768).  LDS double-buffer, ONE barrier per K-tile, write-early
// staging: per tile t -> stage regs(t+1) into buf^1 (vmcnt window = full
// previous iteration), issue loads(t+2), ds_read buf + MFMA, barrier.
// ---------------------------------------------------------------------------
struct GJob { const short* A; const short* Bt; const float* bias;
              short* Cb; float* Cf; int M, Ks, Kl, kOff, mode; float smul; };
struct GArgs { GJob j[5]; int base[6]; };

__global__ __launch_bounds__(256) void gemm_in(GArgs ga) {
    int bid = blockIdx.x;
    int jj = 0;
    while (bid >= ga.base[jj + 1]) jj++;
    GJob jb = ga.j[jj];
    const int local = bid - ga.base[jj];

    __shared__ short As[2][128 * 32];
    __shared__ short Bs[2][64 * 32];

    const int tid  = threadIdx.x;
    const int nB   = (local & 3) * 64;
    const int rB   = (local >> 2) * 128;
    const int w    = tid >> 6;
    const int lane = tid & 63;
    const int l15  = lane & 15;
    const int quad = lane >> 4;
    const int M = jb.M, Ks = jb.Ks, kOff = jb.kOff;
    const int nT = jb.Kl >> 5;

    f32x4 acc[2][4];
#pragma unroll
    for (int i = 0; i < 2; i++)
#pragma unroll
        for (int jt = 0; jt < 4; jt++) acc[i][jt] = (f32x4){0.f, 0.f, 0.f, 0.f};

    const int ra = tid >> 1, k0 = (tid & 1) * 16;   // A staging
    const int rga = rB + ra;
    const int bb = rga / 2500, hwp = rga % 2500;    // mode 1 row decode
    const int nb_ = tid >> 2, gkb = tid & 3;        // B staging
    const int g0 = k0 >> 3;

    short8 pa0 = {0,0,0,0,0,0,0,0}, pa1 = pa0, pb = pa0;

#define GLOADT(t) do {                                                        \
        int kk = kOff + (t) * 32 + k0;                                        \
        if (rga < M) {                                                        \
            const short* p;                                                   \
            if (jb.mode) {                                                    \
                int cam = kk >> 8, c = kk & 255;                              \
                p = &jb.A[(((size_t)(bb * 6 + cam)) * HW + hwp) * DIM + c];   \
            } else {                                                          \
                p = &jb.A[(size_t)rga * Ks + kk];                             \
            }                                                                 \
            pa0 = *(const short8*)p; pa1 = *(const short8*)(p + 8);           \
        }                                                                     \
        pb = *(const short8*)&jb.Bt[(size_t)(nB + nb_) * Ks                   \
                                    + kOff + (t) * 32 + gkb * 8];             \
    } while (0)

#define STAGET(bf) do {                                                       \
        *(short8*)&As[bf][ra * 32 + ((g0 ^ (ra & 3)) << 3)]       = pa0;      \
        *(short8*)&As[bf][ra * 32 + (((g0 + 1) ^ (ra & 3)) << 3)] = pa1;      \
        *(short8*)&Bs[bf][nb_ * 32 + ((gkb ^ (nb_ & 3)) << 3)]    = pb;       \
    } while (0)

    // prologue: tile 0 -> buf0; issue tile 1 loads
    GLOADT(0);
    STAGET(0);
    if (nT > 1) GLOADT(1);
    __syncthreads();

    int cur = 0;
    for (int t = 0; t < nT; t++) {
        // stage tile t+1 (regs, loaded last iter) into the other buffer.
        // Safe: reads of buf[cur^1] (tile t-1) completed before the barrier
        // that ended epoch t-1.
        if (t + 1 < nT) STAGET(cur ^ 1);
        // issue loads for tile t+2 (consumed at stage in epoch t+1)
        if (t + 2 < nT) GLOADT(t + 2);
        // compute tile t from buf[cur]
        short8 af[2], bfr[4];
#pragma unroll
        for (int i = 0; i < 2; i++) {
            int m = w * 32 + i * 16 + l15;
            af[i] = *(const short8*)&As[cur][m * 32 + ((quad ^ (m & 3)) << 3)];
        }
#pragma unroll
        for (int jt = 0; jt < 4; jt++) {
            int n = jt * 16 + l15;
            bfr[jt] = *(const short8*)&Bs[cur][n * 32 + ((quad ^ (n & 3)) << 3)];
        }
#pragma unroll
        for (int i = 0; i < 2; i++)
#pragma unroll
            for (int jt = 0; jt < 4; jt++)
                acc[i][jt] = __builtin_amdgcn_mfma_f32_16x16x32_bf16(
                    af[i], bfr[jt], acc[i][jt], 0, 0, 0);
        if (t + 1 < nT) { __syncthreads(); cur ^= 1; }
    }
#undef GLOADT
#undef STAGET

#pragma unroll
    for (int i = 0; i < 2; i++) {
        int rbase = rB + w * 32 + i * 16 + quad * 4;
#pragma unroll
        for (int jt = 0; jt < 4; jt++) {
            int col = nB + jt * 16 + l15;
            float bcol = jb.bias ? jb.bias[col] : 0.f;
#pragma unroll
            for (int reg = 0; reg < 4; reg++) {
                int rr = rbase + reg;
                if (rr < M) {
                    float vv = (acc[i][jt][reg] + bcol) * jb.smul;
                    if (jb.Cb) jb.Cb[(size_t)rr * 256 + col] = f2bf(vv);
                    else       jb.Cf[(size_t)rr * 256 + col] = vv;
                }
            }
        }
    }
}

// ---------------------------------------------------------------------------
// Tail GEMM, R10: same single-barrier write-early LDS double-buffer as
// gemm_in (harness-proven).  BM=128 (RT=2).
// EPI 0: bias; 1: bias+GELU; 2: bias+res(+res2).  WF32: fp32 C; WBF: bf16 C2.
// ---------------------------------------------------------------------------
template<int EPI, int WF32, int WBF>
__global__ __launch_bounds__(256) void mgemm_bf(
    const short* __restrict__ A, const short* __restrict__ Bt,
    const float* __restrict__ bias, const float* __restrict__ res,
    const float* __restrict__ res2,
    float* __restrict__ C, short* __restrict__ C2, int M, int N, int K)
{
    __shared__ short As[2][128 * 32];
    __shared__ short Bs[2][64 * 32];

    const int tid  = threadIdx.x;
    const int nB   = blockIdx.x * 64;
    const int rB   = blockIdx.y * 128;
    const int w    = tid >> 6;
    const int lane = tid & 63;
    const int l15  = lane & 15;
    const int quad = lane >> 4;
    const int nT   = K >> 5;

    f32x4 acc[2][4];
#pragma unroll
    for (int i = 0; i < 2; i++)
#pragma unroll
        for (int jt = 0; jt < 4; jt++) acc[i][jt] = (f32x4){0.f, 0.f, 0.f, 0.f};

    const int ra = tid >> 1, k0 = (tid & 1) * 16;
    const int rga = rB + ra;
    const int nb_ = tid >> 2, gkb = tid & 3;
    const int g0 = k0 >> 3;

    short8 pa0 = {0,0,0,0,0,0,0,0}, pa1 = pa0, pb = pa0;

#define MGLOAD(t) do {                                                        \
        if (rga < M) {                                                        \
            const short* p = &A[(size_t)rga * K + (t) * 32 + k0];             \
            pa0 = *(const short8*)p; pa1 = *(const short8*)(p + 8);           \
        }                                                                     \
        pb = *(const short8*)&Bt[(size_t)(nB + nb_) * K + (t) * 32 + gkb * 8];\
    } while (0)

#define MSTAGE(bf) do {                                                       \
        *(short8*)&As[bf][ra * 32 + ((g0 ^ (ra & 3)) << 3)]       = pa0;      \
        *(short8*)&As[bf][ra * 32 + (((g0 + 1) ^ (ra & 3)) << 3)] = pa1;      \
        *(short8*)&Bs[bf][nb_ * 32 + ((gkb ^ (nb_ & 3)) << 3)]    = pb;       \
    } while (0)

    // prologue: tile 0 -> buf0; issue tile 1 loads
    MGLOAD(0);
    MSTAGE(0);
    if (nT > 1) MGLOAD(1);
    __syncthreads();

    int cur = 0;
    for (int t = 0; t < nT; t++) {
        if (t + 1 < nT) MSTAGE(cur ^ 1);
        if (t + 2 < nT) MGLOAD(t + 2);
        short8 af[2], bfr[4];
#pragma unroll
        for (int i = 0; i < 2; i++) {
            int m = w * 32 + i * 16 + l15;
            af[i] = *(const short8*)&As[cur][m * 32 + ((quad ^ (m & 3)) << 3)];
        }
#pragma unroll
        for (int jt = 0; jt < 4; jt++) {
            int n = jt * 16 + l15;
            bfr[jt] = *(const short8*)&Bs[cur][n * 32 + ((quad ^ (n & 3)) << 3)];
        }
#pragma unroll
        for (int i = 0; i < 2; i++)
#pragma unroll
            for (int jt = 0; jt < 4; jt++)
                acc[i][jt] = __builtin_amdgcn_mfma_f32_16x16x32_bf16(
                    af[i], bfr[jt], acc[i][jt], 0, 0, 0);
        if (t + 1 < nT) { __syncthreads(); cur ^= 1; }
    }
#undef MGLOAD
#undef MSTAGE

#pragma unroll
    for (int i = 0; i < 2; i++) {
        int rbase = rB + w * 32 + i * 16 + quad * 4;
#pragma unroll
        for (int jt = 0; jt < 4; jt++) {
            int col = nB + jt * 16 + l15;
            float bcol = bias[col];
#pragma unroll
            for (int reg = 0; reg < 4; reg++) {
                int rr = rbase + reg;
                if (rr < M) {
                    float vv = acc[i][jt][reg] + bcol;
                    if (EPI == 1) vv = 0.5f * vv * (1.f + erff(vv * 0.70710678118654752f));
                    if (EPI == 2) {
                        vv += res[(size_t)rr * N + col];
                        if (res2) vv += res2[(size_t)rr * N + col];
                    }
                    if (WF32) C[(size_t)rr * N + col] = vv;
                    if (WBF)  C2[(size_t)rr * N + col] = f2bf(vv);
                }
            }
        }
    }
}

// ---------------------------------------------------------------------------
// MFMA attention — byte-identical to the R7-passing version.
// P in registers via kappa-permuted swapped QK^T; Z on the MFMA pipe
// (ones-fragment).  Single LDS buffer, two barriers per chunk.
// ---------------------------------------------------------------------------
#define TQA 64
#define CH 64
#define VSTR 72

__global__ __launch_bounds__(256) void attn_mfma(
    const short* __restrict__ qf, const short* __restrict__ kf,
    const short* __restrict__ vf, short* __restrict__ attn_out,
    float* __restrict__ Zp)
{
    const int qt  = blockIdx.x;
    const int bm  = blockIdx.y;
    const int cam = blockIdx.z;
    const int b = bm >> 3, m = bm & 7;
    const int q0 = qt * TQA;
    const int tid = threadIdx.x;
    const int w = tid >> 6, lane = tid & 63;
    const int l15 = lane & 15, quad = lane >> 4;

    __shared__ __align__(16) short Ks[CH][DH];
    __shared__ __align__(16) short Vt[DH][VSTR];

    const size_t slab = (size_t)(b * 6 + cam);

    int qrow = q0 + w * 16 + l15;
    int qcl  = qrow < HW ? qrow : HW - 1;
    const short8 aq = *(const short8*)&qf[(slab * HW + qcl) * DIM + m * DH + quad * 8];

    const short* kb = kf + slab * KP * DIM + m * DH;
    const short* vb = vf + slab * KP * DIM + m * DH;

    f32x4 oacc[2];
    oacc[0] = (f32x4){0.f, 0.f, 0.f, 0.f};
    oacc[1] = (f32x4){0.f, 0.f, 0.f, 0.f};
    f32x4 zacc = (f32x4){0.f, 0.f, 0.f, 0.f};
    const short one_bf = (short)0x3F80;                 // bf16 1.0
    const short8 ones8 = {one_bf, one_bf, one_bf, one_bf,
                          one_bf, one_bf, one_bf, one_bf};

    // K staging: one b128 per thread, kappa-permuted destination row
    const int kl = tid >> 2, d8 = (tid & 3) * 8;
    const int jtw  = ((kl >> 5) & 1) | (((kl >> 2) & 1) << 1);
    const int rw   = (((kl >> 3) & 3) << 2) | (kl & 3);
    const int krow = jtw * 16 + rw;
    // V pair staging: two adjacent keys, 4 dh each -> 4 ds_write_b32
    const int kp2 = tid >> 3, dv = (tid & 7) * 4;
    const int vcol2 = (((kp2 >> 2) ^ (dv >> 3)) << 3) | ((2 * kp2) & 7);

    for (int c0 = 0; c0 < KP; c0 += CH) {
        __syncthreads();
        {
            int key = c0 + kl;
            short8 kv8 = {0, 0, 0, 0, 0, 0, 0, 0};
            if (key < KP) kv8 = *(const short8*)&kb[(size_t)key * DIM + d8];
            *(short8*)&Ks[krow][d8] = kv8;

            int k0v = c0 + 2 * kp2;
            uint2 a0 = {0u, 0u}, a1 = {0u, 0u};
            if (k0v < KP)     a0 = *(const uint2*)&vb[(size_t)k0v * DIM + dv];
            if (k0v + 1 < KP) a1 = *(const uint2*)&vb[(size_t)(k0v + 1) * DIM + dv];
            // interleave keys: (v0[t] | v1[t]<<16) via v_perm_b32
            *(unsigned*)&Vt[dv + 0][vcol2] = __builtin_amdgcn_perm(a1.x, a0.x, 0x05040100u);
            *(unsigned*)&Vt[dv + 1][vcol2] = __builtin_amdgcn_perm(a1.x, a0.x, 0x07060302u);
            *(unsigned*)&Vt[dv + 2][vcol2] = __builtin_amdgcn_perm(a1.y, a0.y, 0x05040100u);
            *(unsigned*)&Vt[dv + 3][vcol2] = __builtin_amdgcn_perm(a1.y, a0.y, 0x07060302u);
        }
        __syncthreads();
        // swapped QK^T over kappa-permuted K rows
        f32x4 sfragT[4];
#pragma unroll
        for (int jt = 0; jt < 4; jt++) {
            short8 bk8 = *(const short8*)&Ks[jt * 16 + l15][quad * 8];
            sfragT[jt] = __builtin_amdgcn_mfma_f32_16x16x32_bf16(
                bk8, aq, (f32x4){0.f, 0.f, 0.f, 0.f}, 0, 0, 0);
        }
        // softmax numerator -> in-register PV A-fragments
        union PA { unsigned u[4]; short8 s8; } pa[2];
        if (c0 + CH <= KP) {   // full chunk (0..8): no key masking
#pragma unroll
            for (int jt = 0; jt < 4; jt++) {
                float e0 = exp2_hw(sfragT[jt][0]);
                float e1 = exp2_hw(sfragT[jt][1]);
                float e2 = exp2_hw(sfragT[jt][2]);
                float e3 = exp2_hw(sfragT[jt][3]);
                asm("v_cvt_pk_bf16_f32 %0, %1, %2"
                    : "=v"(pa[jt & 1].u[(jt >> 1) * 2]) : "v"(e0), "v"(e1));
                asm("v_cvt_pk_bf16_f32 %0, %1, %2"
                    : "=v"(pa[jt & 1].u[(jt >> 1) * 2 + 1]) : "v"(e2), "v"(e3));
            }
        } else {               // tail chunk: mask keys >= KP
            int kq8 = c0 + quad * 8;
#pragma unroll
            for (int jt = 0; jt < 4; jt++) {
                int kb0 = kq8 + (jt & 1) * 32 + ((jt >> 1) << 2);
                float e0 = (kb0 + 0 < KP) ? exp2_hw(sfragT[jt][0]) : 0.f;
                float e1 = (kb0 + 1 < KP) ? exp2_hw(sfragT[jt][1]) : 0.f;
                float e2 = (kb0 + 2 < KP) ? exp2_hw(sfragT[jt][2]) : 0.f;
                float e3 = (kb0 + 3 < KP) ? exp2_hw(sfragT[jt][3]) : 0.f;
                asm("v_cvt_pk_bf16_f32 %0, %1, %2"
                    : "=v"(pa[jt & 1].u[(jt >> 1) * 2]) : "v"(e0), "v"(e1));
                asm("v_cvt_pk_bf16_f32 %0, %1, %2"
                    : "=v"(pa[jt & 1].u[(jt >> 1) * 2 + 1]) : "v"(e2), "v"(e3));
            }
        }
        // PV: A-fragment direct from registers; Z rides the MFMA pipe
#pragma unroll
        for (int ks = 0; ks < 2; ks++) {
#pragma unroll
            for (int nt = 0; nt < 2; nt++) {
                int dhn = nt * 16 + l15;
                int pgrp = ((ks * 4 + quad) ^ (dhn >> 3));
                short8 bv8 = *(const short8*)&Vt[dhn][pgrp << 3];
                oacc[nt] = __builtin_amdgcn_mfma_f32_16x16x32_bf16(
                    pa[ks].s8, bv8, oacc[nt], 0, 0, 0);
            }
            zacc = __builtin_amdgcn_mfma_f32_16x16x32_bf16(
                pa[ks].s8, ones8, zacc, 0, 0, 0);
        }
    }
    // zacc rows = q (quad*4+reg); all 16 cols identical -> write from l15==0
    if (l15 == 0) {
#pragma unroll
        for (int reg = 0; reg < 4; reg++) {
            int q = q0 + w * 16 + quad * 4 + reg;
            if (q < HW) Zp[((size_t)bm * 6 + cam) * HW + q] = zacc[reg];
        }
    }
#pragma unroll
    for (int reg = 0; reg < 4; reg++) {
        int q = q0 + w * 16 + quad * 4 + reg;
        if (q < HW) {
            size_t rowb = ((size_t)b * HW + q) * NDIM + cam * DIM + m * DH;
            attn_out[rowb + l15]      = f2bf(oacc[0][reg]);
            attn_out[rowb + 16 + l15] = f2bf(oacc[1][reg]);
        }
    }
}

// ---------------------------------------------------------------------------
// LayerNorm over 1536 (bf16 in) + fused joint-softmax normalization -> bf16.
// ---------------------------------------------------------------------------
__global__ __launch_bounds__(256) void ln_pre_kernel(
    const short* __restrict__ xin, short* __restrict__ lnbf,
    const float* __restrict__ Zp,
    const float* __restrict__ g, const float* __restrict__ bt)
{
    const int row = blockIdx.x;
    const int tid = threadIdx.x;
    const int b = row / 2500, q = row % 2500;
    __shared__ float zinv[8];
    if (tid < 8) {
        float z = 0.f;
#pragma unroll
        for (int cam = 0; cam < 6; cam++)
            z += Zp[((size_t)(b * 8 + tid) * 6 + cam) * HW + q];
        zinv[tid] = 1.f / z;
    }
    __syncthreads();
    const short* p = xin + (size_t)row * NDIM;
    float v[6];
    float s = 0.f, ss = 0.f;
#pragma unroll
    for (int i = 0; i < 6; i++) {
        int c = tid + i * 256;
        v[i] = bf2f(p[c]) * zinv[(c >> 5) & 7];
        s += v[i]; ss += v[i] * v[i];
    }
    __shared__ float rs[4], rss[4];
    int lane = tid & 63, wid = tid >> 6;
#pragma unroll
    for (int o = 32; o > 0; o >>= 1) { s += __shfl_down(s, o); ss += __shfl_down(ss, o); }
    if (lane == 0) { rs[wid] = s; rss[wid] = ss; }
    __syncthreads();
    s = rs[0] + rs[1] + rs[2] + rs[3];
    ss = rss[0] + rss[1] + rss[2] + rss[3];
    float mu = s * (1.f / NDIM);
    float var = ss * (1.f / NDIM) - mu * mu;
    float inv = rsqrtf(var + 1e-5f);
#pragma unroll
    for (int i = 0; i < 6; i++) {
        int c = tid + i * 256;
        lnbf[(size_t)row * NDIM + c] = f2bf((v[i] - mu) * inv * g[c] + bt[c]);
    }
}

// ---------------------------------------------------------------------------
// final2 (as R7): coalesced transpose store.
// ---------------------------------------------------------------------------
__global__ __launch_bounds__(256) void final_kernel2(
    const float* __restrict__ x, const float* __restrict__ y2,
    const float* __restrict__ g, const float* __restrict__ bt,
    float* __restrict__ out)
{
    __shared__ float T[256][33];
    __shared__ float ps[32][8], pss[32][8];
    __shared__ float mu_s[32], inv_s[32];
    const int tid = threadIdx.x;
    const int rl = tid & 31, seg = tid >> 5;
    const int r0 = blockIdx.x * 32;
    const int row = r0 + rl;
    const bool ok = row < 5000;

    float4 yv[8];
    float s = 0.f, ss = 0.f;
    if (ok) {
        const float4* yp = (const float4*)(y2 + (size_t)row * DIM + seg * 32);
#pragma unroll
        for (int j = 0; j < 8; j++) {
            yv[j] = yp[j];
            s += yv[j].x + yv[j].y + yv[j].z + yv[j].w;
            ss += yv[j].x * yv[j].x + yv[j].y * yv[j].y
                + yv[j].z * yv[j].z + yv[j].w * yv[j].w;
        }
    } else {
#pragma unroll
        for (int j = 0; j < 8; j++) yv[j] = (float4){0, 0, 0, 0};
    }
    ps[rl][seg] = s; pss[rl][seg] = ss;
    __syncthreads();
    if (tid < 32) {
        float a = 0.f, b2 = 0.f;
#pragma unroll
        for (int j = 0; j < 8; j++) { a += ps[tid][j]; b2 += pss[tid][j]; }
        float mu = a * (1.f / DIM);
        float var = b2 * (1.f / DIM) - mu * mu;
        mu_s[tid] = mu;
        inv_s[tid] = rsqrtf(var + 1e-5f);
    }
    __syncthreads();
    if (ok) {
        float mu = mu_s[rl], inv = inv_s[rl];
        const float4* xp = (const float4*)(x + (size_t)row * DIM + seg * 32);
#pragma unroll
        for (int j = 0; j < 8; j++) {
            float4 xv = xp[j];
            int c = seg * 32 + j * 4;
            T[c + 0][rl] = xv.x + (yv[j].x - mu) * inv * g[c + 0] + bt[c + 0];
            T[c + 1][rl] = xv.y + (yv[j].y - mu) * inv * g[c + 1] + bt[c + 1];
            T[c + 2][rl] = xv.z + (yv[j].z - mu) * inv * g[c + 2] + bt[c + 2];
            T[c + 3][rl] = xv.w + (yv[j].w - mu) * inv * g[c + 3] + bt[c + 3];
        }
    }
    __syncthreads();
    const int w = tid >> 6, lane = tid & 63;
    const int hl = lane & 31, ch = lane >> 5;
    const int rr = r0 + hl;
    if (rr < 5000) {
        int b = rr / 2500, hw = rr % 2500;
        size_t obase = (size_t)b * 640000 + hw;
#pragma unroll
        for (int it = 0; it < 32; it++) {
            int c = it * 8 + w * 2 + ch;
            out[obase + (size_t)c * 2500] = T[c][hl];
        }
    }
}

// ---------------------------------------------------------------------------
extern "C" void kernel_launch(void* const* d_in, const int* in_sizes, int n_in,
                              void* d_out, int out_size, void* d_ws, size_t ws_size,
                              hipStream_t stream)
{
    const float* q     = (const float*)d_in[0];
    const float* k     = (const float*)d_in[1];
    const float* v     = (const float*)d_in[2];
    const float* Wq    = (const float*)d_in[3];
    const float* bq    = (const float*)d_in[4];
    const float* Wk    = (const float*)d_in[5];
    const float* bk    = (const float*)d_in[6];
    const float* Wv    = (const float*)d_in[7];
    const float* bv    = (const float*)d_in[8];
    const float* Wproj = (const float*)d_in[9];
    const float* bproj = (const float*)d_in[10];
    const float* Waddq = (const float*)d_in[11];
    const float* baddq = (const float*)d_in[12];
    const float* W1    = (const float*)d_in[13];
    const float* b1    = (const float*)d_in[14];
    const float* W2    = (const float*)d_in[15];
    const float* b2    = (const float*)d_in[16];
    const float* g_pre = (const float*)d_in[17];
    const float* b_pre = (const float*)d_in[18];
    const float* g_nrm = (const float*)d_in[19];
    const float* b_nrm = (const float*)d_in[20];
    float* out = (float*)d_out;

    // workspace layout (float-unit offsets)
    float* ws = (float*)d_ws;
    short* qf_a   = (short*)(ws);             // [0, 3.84M)
    short* lnbf   = (short*)(ws);             //   alias after attn
    short* qbf    = (short*)(ws + 3840000);   // [3.84M, 7.68M)
    short* kf_a   = (short*)(ws + 7680000);   // [7.68M, 8.64M)
    short* kpbf   = (short*)(ws + 8640000);   // [8.64M, 9.6M)
    short* vf_a   = (short*)(ws + 9600000);   // [9.6M, 10.56M)
    short* vpbf   = (short*)(ws + 10560000);  // [10.56M, 11.52M)
    float* add_q  = ws + 11520000;            // [11.52M, 12.8M)
    short* attn_o = (short*)(ws + 12800000);  // bf16: [12.8M, 16.64M)
    short* xbf    = (short*)(ws + 12800000);  //   alias: live only after ln_pre
    short* h1bf   = (short*)(ws + 13440000);  //   alias: [13.44M, 14.72M)
    float* add_q2 = ws + 16640000;            // [16.64M, 17.92M) split-K partial
    float* x      = ws + 20480000;            // [20.48M, 21.76M)
    float* Zp     = ws + 21760000;            // [21.76M, 22M)
    short* eW     = (short*)(ws + 22000000);
    short* Wq_t    = eW;
    short* Wk_t    = eW + 65536;
    short* Wv_t    = eW + 131072;
    short* Waddq_t = eW + 196608;
    short* lW     = (short*)(ws + 22295000);
    short* Wproj_t = lW;
    short* W1_t    = lW + 393216;
    short* W2_t    = lW + 524288;
    float* y2     = ws + 22625000;            // [22.62M, 23.9M)

    dim3 blk(256);

    // 1) all conversion work in one launch
    {
        WArgs wa;
        wa.j[0] = {Wq,    Wq_t,    256,  256};
        wa.j[1] = {Wk,    Wk_t,    256,  256};
        wa.j[2] = {Wv,    Wv_t,    256,  256};
        wa.j[3] = {Waddq, Waddq_t, 1536, 256};
        wa.j[4] = {Wproj, Wproj_t, 1536, 256};
        wa.j[5] = {W1,    W1_t,    256,  512};
        wa.j[6] = {W2,    W2_t,    512,  256};
        prep_all<<<dim3(12640), blk, 0, stream>>>(q, k, v, qbf, kpbf, vpbf, wa);
    }
    // 2) all input-side GEMMs, flat grid: long add_q blocks first (HW
    //    round-robin spreads them across XCDs) + split-K(2x768)
    //    qf job pre-scales by softmax scale * log2e (consumed only by attn)
    {
        GArgs ga;
        //          A     Bt       bias     Cb       Cf      M      Ks    Kl   kOff mode smul
        ga.j[0] = {qbf,  Waddq_t, baddq,   nullptr, add_q,  5000,  1536, 768, 0,   1, 1.0f};
        ga.j[1] = {qbf,  Waddq_t, nullptr, nullptr, add_q2, 5000,  1536, 768, 768, 1, 1.0f};
        ga.j[2] = {qbf,  Wq_t,    bq,      qf_a,    nullptr, 30000, 256, 256, 0,   0, SCALE_LOG2E};
        ga.j[3] = {kpbf, Wk_t,    bk,      kf_a,    nullptr, 7500,  256, 256, 0,   0, 1.0f};
        ga.j[4] = {vpbf, Wv_t,    bv,      vf_a,    nullptr, 7500,  256, 256, 0,   0, 1.0f};
        int cnt[5] = {160, 160, 940, 236, 236};   // 40*4, 40*4, 235*4, 59*4, 59*4
        ga.base[0] = 0;
        for (int i = 0; i < 5; i++) ga.base[i + 1] = ga.base[i] + cnt[i];
        gemm_in<<<dim3(ga.base[5]), blk, 0, stream>>>(ga);
    }
    // 3) attention (bf16 out, P in registers, Z on MFMA pipe) — R7-proven
    attn_mfma<<<dim3(40, 16, 6), blk, 0, stream>>>(qf_a, kf_a, vf_a, attn_o, Zp);
    // 4) LN(1536) + softmax-normalize -> bf16 (into dead qf_a region)
    ln_pre_kernel<<<dim3(5000), blk, 0, stream>>>(attn_o, lnbf, Zp, g_pre, b_pre);
    // 5) x = ln @ Wproj + bproj + add_q + add_q2  (fp32 x + bf16 xbf)
    mgemm_bf<2, 1, 1><<<dim3(4, 40), blk, 0, stream>>>(
        lnbf, Wproj_t, bproj, add_q, add_q2, x, xbf, 5000, 256, 1536);
    // 6) h1 = gelu(x @ W1 + b1) -> bf16
    mgemm_bf<1, 0, 1><<<dim3(8, 40), blk, 0, stream>>>(
        xbf, W1_t, b1, nullptr, nullptr, nullptr, h1bf, 5000, 512, 256);
    // 7) y2 = h1 @ W2 + b2 -> fp32
    mgemm_bf<0, 1, 0><<<dim3(4, 40), blk, 0, stream>>>(
        h1bf, W2_t, b2, nullptr, nullptr, y2, nullptr, 5000, 256, 512);
    // 8) out = transpose(x + LN256(y2)) — coalesced
    final_kernel2<<<dim3(157), blk, 0, stream>>>(x, y2, g_nrm, b_nrm, out);
}

// Round 12
// 305.931 us; speedup vs baseline: 1.0402x; 1.0334x over previous
//
#include <hip/hip_runtime.h>
#include <math.h>

// Problem constants
#define BATCH 2
#define NCAM 6
#define DIM 256
#define HEADS 8
#define DH 32
#define HW 2500          // 50*50
#define KP 625           // 25*25 pooled keys per cam
#define NDIM (NCAM*DIM)  // 1536

// scale/sqrt(dh) folded with log2(e) into the qf GEMM epilogue:
// 1.4426950408889634 / sqrt(32) = 0.25503488494404
#define SCALE_LOG2E 0.25503488494404f

typedef __attribute__((ext_vector_type(8))) short short8;
typedef __attribute__((ext_vector_type(4))) float f32x4;

__device__ __forceinline__ short f2bf(float f) {
    union { float f; unsigned u; } v; v.f = f;
    unsigned r = v.u + 0x7fffu + ((v.u >> 16) & 1u);   // round-to-nearest-even
    return (short)(r >> 16);
}
__device__ __forceinline__ float bf2f(short h) {
    union { unsigned u; float f; } v; v.u = ((unsigned)(unsigned short)h) << 16;
    return v.f;
}
// 2^x via the HW base-2 exp instruction
__device__ __forceinline__ float exp2_hw(float x) {
    return __builtin_amdgcn_exp2f(x);
}

// ---------------------------------------------------------------------------
// prep_all: ALL one-time data conversion in ONE launch (as R7).
// ---------------------------------------------------------------------------
struct WJ { const float* src; short* dst; int K, N; };
struct WArgs { WJ j[7]; };

__global__ __launch_bounds__(256) void prep_all(
    const float* __restrict__ q, const float* __restrict__ k,
    const float* __restrict__ v, short* __restrict__ qbf,
    short* __restrict__ kpbf, short* __restrict__ vpbf, WArgs wa)
{
    __shared__ float t[32][33];
    const int tx = threadIdx.x & 31, ty = threadIdx.x >> 5;   // ty 0..7
    int i = blockIdx.x;
    if (i < 7584) {
        int slab = i / 632, rem = i % 632;
        int hwB = (rem % 79) * 32, dB = (rem / 79) * 32;
        const float* src = q + (size_t)slab * 640000;
#pragma unroll
        for (int ii = 0; ii < 32; ii += 8) {
            int hw = hwB + tx;
            t[ty + ii][tx] = (hw < HW) ? src[(size_t)(dB + ty + ii) * HW + hw] : 0.f;
        }
        __syncthreads();
#pragma unroll
        for (int ii = 0; ii < 32; ii += 8) {
            int hw = hwB + ty + ii;
            if (hw < HW)
                qbf[((size_t)slab * HW + hw) * DIM + dB + tx] = f2bf(t[tx][ty + ii]);
        }
    } else if (i < 11424) {
        int i2 = i - 7584;
        const float* base; short* dst;
        if (i2 < 1920) { base = k; dst = kpbf; }
        else           { base = v; dst = vpbf; i2 -= 1920; }
        int slab = i2 / 160, rem = i2 % 160;
        int kpB = (rem % 20) * 32, dB = (rem / 20) * 32;
        const float* src = base + (size_t)slab * 640000;
        dst += (size_t)slab * (KP * DIM);
#pragma unroll
        for (int ii = 0; ii < 32; ii += 8) {
            int kp = kpB + tx;
            float val = 0.f;
            if (kp < KP) {
                int r2 = (kp / 25) * 2, c2 = (kp % 25) * 2;
                const float* p0 = src + (size_t)(dB + ty + ii) * HW + r2 * 50 + c2;
                val = 0.25f * (p0[0] + p0[1] + p0[50] + p0[51]);
            }
            t[ty + ii][tx] = val;
        }
        __syncthreads();
#pragma unroll
        for (int ii = 0; ii < 32; ii += 8) {
            int kp = kpB + ty + ii;
            if (kp < KP)
                dst[(size_t)kp * DIM + dB + tx] = f2bf(t[tx][ty + ii]);
        }
    } else {
        int wi = i - 11424;
        WJ jb = wa.j[0];
        for (int jj = 0; jj < 7; jj++) {
            jb = wa.j[jj];
            int cnt = (jb.K >> 5) * (jb.N >> 5);
            if (wi < cnt) break;
            wi -= cnt;
        }
        int tn = jb.N >> 5;
        int nB = (wi % tn) * 32, kB = (wi / tn) * 32;
#pragma unroll
        for (int ii = 0; ii < 32; ii += 8)
            t[ty + ii][tx] = jb.src[(size_t)(kB + ty + ii) * jb.N + nB + tx];
        __syncthreads();
#pragma unroll
        for (int ii = 0; ii < 32; ii += 8)
            jb.dst[(size_t)(nB + ty + ii) * jb.K + kB + tx] = f2bf(t[tx][ty + ii]);
    }
}

// ---------------------------------------------------------------------------
// Batched input GEMMs (R6-proven): flat 1D grid, add_q split-K (2x768),
// LDS double-buffer, ONE barrier per K-tile, write-early staging.
// ---------------------------------------------------------------------------
struct GJob { const short* A; const short* Bt; const float* bias;
              short* Cb; float* Cf; int M, Ks, Kl, kOff, mode; float smul; };
struct GArgs { GJob j[5]; int base[6]; };

__global__ __launch_bounds__(256) void gemm_in(GArgs ga) {
    int bid = blockIdx.x;
    int jj = 0;
    while (bid >= ga.base[jj + 1]) jj++;
    GJob jb = ga.j[jj];
    const int local = bid - ga.base[jj];

    __shared__ short As[2][128 * 32];
    __shared__ short Bs[2][64 * 32];

    const int tid  = threadIdx.x;
    const int nB   = (local & 3) * 64;
    const int rB   = (local >> 2) * 128;
    const int w    = tid >> 6;
    const int lane = tid & 63;
    const int l15  = lane & 15;
    const int quad = lane >> 4;
    const int M = jb.M, Ks = jb.Ks, kOff = jb.kOff;
    const int nT = jb.Kl >> 5;

    f32x4 acc[2][4];
#pragma unroll
    for (int i = 0; i < 2; i++)
#pragma unroll
        for (int jt = 0; jt < 4; jt++) acc[i][jt] = (f32x4){0.f, 0.f, 0.f, 0.f};

    const int ra = tid >> 1, k0 = (tid & 1) * 16;   // A staging
    const int rga = rB + ra;
    const int bb = rga / 2500, hwp = rga % 2500;    // mode 1 row decode
    const int nb_ = tid >> 2, gkb = tid & 3;        // B staging
    const int g0 = k0 >> 3;

    short8 pa0 = {0,0,0,0,0,0,0,0}, pa1 = pa0, pb = pa0;

#define GLOADT(t) do {                                                        \
        int kk = kOff + (t) * 32 + k0;                                        \
        if (rga < M) {                                                        \
            const short* p;                                                   \
            if (jb.mode) {                                                    \
                int cam = kk >> 8, c = kk & 255;                              \
                p = &jb.A[(((size_t)(bb * 6 + cam)) * HW + hwp) * DIM + c];   \
            } else {                                                          \
                p = &jb.A[(size_t)rga * Ks + kk];                             \
            }                                                                 \
            pa0 = *(const short8*)p; pa1 = *(const short8*)(p + 8);           \
        }                                                                     \
        pb = *(const short8*)&jb.Bt[(size_t)(nB + nb_) * Ks                   \
                                    + kOff + (t) * 32 + gkb * 8];             \
    } while (0)

#define STAGET(bf) do {                                                       \
        *(short8*)&As[bf][ra * 32 + ((g0 ^ (ra & 3)) << 3)]       = pa0;      \
        *(short8*)&As[bf][ra * 32 + (((g0 + 1) ^ (ra & 3)) << 3)] = pa1;      \
        *(short8*)&Bs[bf][nb_ * 32 + ((gkb ^ (nb_ & 3)) << 3)]    = pb;       \
    } while (0)

    // prologue: tile 0 -> buf0; issue tile 1 loads
    GLOADT(0);
    STAGET(0);
    if (nT > 1) GLOADT(1);
    __syncthreads();

    int cur = 0;
    for (int t = 0; t < nT; t++) {
        if (t + 1 < nT) STAGET(cur ^ 1);
        if (t + 2 < nT) GLOADT(t + 2);
        short8 af[2], bfr[4];
#pragma unroll
        for (int i = 0; i < 2; i++) {
            int m = w * 32 + i * 16 + l15;
            af[i] = *(const short8*)&As[cur][m * 32 + ((quad ^ (m & 3)) << 3)];
        }
#pragma unroll
        for (int jt = 0; jt < 4; jt++) {
            int n = jt * 16 + l15;
            bfr[jt] = *(const short8*)&Bs[cur][n * 32 + ((quad ^ (n & 3)) << 3)];
        }
#pragma unroll
        for (int i = 0; i < 2; i++)
#pragma unroll
            for (int jt = 0; jt < 4; jt++)
                acc[i][jt] = __builtin_amdgcn_mfma_f32_16x16x32_bf16(
                    af[i], bfr[jt], acc[i][jt], 0, 0, 0);
        if (t + 1 < nT) { __syncthreads(); cur ^= 1; }
    }
#undef GLOADT
#undef STAGET

#pragma unroll
    for (int i = 0; i < 2; i++) {
        int rbase = rB + w * 32 + i * 16 + quad * 4;
#pragma unroll
        for (int jt = 0; jt < 4; jt++) {
            int col = nB + jt * 16 + l15;
            float bcol = jb.bias ? jb.bias[col] : 0.f;
#pragma unroll
            for (int reg = 0; reg < 4; reg++) {
                int rr = rbase + reg;
                if (rr < M) {
                    float vv = (acc[i][jt][reg] + bcol) * jb.smul;
                    if (jb.Cb) jb.Cb[(size_t)rr * 256 + col] = f2bf(vv);
                    else       jb.Cf[(size_t)rr * 256 + col] = vv;
                }
            }
        }
    }
}

// ---------------------------------------------------------------------------
// Tail GEMM, R12: BM=64 for 2x grid occupancy (5000/64 = 79 row blocks).
// 4 waves x (16 rows x 64 cols); per K-tile: 1 A-frag + 4 B-frags, 4 MFMA.
// Same single-barrier write-early LDS double-buffer as gemm_in (proven).
// EPI 0: bias; 1: bias+GELU; 2: bias+res(+res2).  WF32: fp32 C; WBF: bf16 C2.
// ---------------------------------------------------------------------------
template<int EPI, int WF32, int WBF>
__global__ __launch_bounds__(256) void mgemm64(
    const short* __restrict__ A, const short* __restrict__ Bt,
    const float* __restrict__ bias, const float* __restrict__ res,
    const float* __restrict__ res2,
    float* __restrict__ C, short* __restrict__ C2, int M, int N, int K)
{
    __shared__ short As[2][64 * 32];
    __shared__ short Bs[2][64 * 32];

    const int tid  = threadIdx.x;
    const int nB   = blockIdx.x * 64;
    const int rB   = blockIdx.y * 64;
    const int w    = tid >> 6;
    const int lane = tid & 63;
    const int l15  = lane & 15;
    const int quad = lane >> 4;
    const int nT   = K >> 5;

    f32x4 acc[4];
#pragma unroll
    for (int jt = 0; jt < 4; jt++) acc[jt] = (f32x4){0.f, 0.f, 0.f, 0.f};

    const int ra4 = tid >> 2, ga = tid & 3;     // A staging: 1 short8/thread
    const int ka  = ga * 8;
    const int rga = rB + ra4;
    const int nb_ = tid >> 2, gkb = tid & 3;    // B staging

    short8 pa0 = {0,0,0,0,0,0,0,0}, pb = pa0;

#define MGLOAD(t) do {                                                        \
        if (rga < M)                                                          \
            pa0 = *(const short8*)&A[(size_t)rga * K + (t) * 32 + ka];        \
        pb = *(const short8*)&Bt[(size_t)(nB + nb_) * K + (t) * 32 + gkb * 8];\
    } while (0)

#define MSTAGE(bf) do {                                                       \
        *(short8*)&As[bf][ra4 * 32 + ((ga ^ (ra4 & 3)) << 3)] = pa0;          \
        *(short8*)&Bs[bf][nb_ * 32 + ((gkb ^ (nb_ & 3)) << 3)] = pb;          \
    } while (0)

    MGLOAD(0);
    MSTAGE(0);
    if (nT > 1) MGLOAD(1);
    __syncthreads();

    int cur = 0;
    for (int t = 0; t < nT; t++) {
        if (t + 1 < nT) MSTAGE(cur ^ 1);
        if (t + 2 < nT) MGLOAD(t + 2);
        short8 af, bfr[4];
        {
            int m = w * 16 + l15;
            af = *(const short8*)&As[cur][m * 32 + ((quad ^ (m & 3)) << 3)];
        }
#pragma unroll
        for (int jt = 0; jt < 4; jt++) {
            int n = jt * 16 + l15;
            bfr[jt] = *(const short8*)&Bs[cur][n * 32 + ((quad ^ (n & 3)) << 3)];
        }
#pragma unroll
        for (int jt = 0; jt < 4; jt++)
            acc[jt] = __builtin_amdgcn_mfma_f32_16x16x32_bf16(
                af, bfr[jt], acc[jt], 0, 0, 0);
        if (t + 1 < nT) { __syncthreads(); cur ^= 1; }
    }
#undef MGLOAD
#undef MSTAGE

    {
        int rbase = rB + w * 16 + quad * 4;
#pragma unroll
        for (int jt = 0; jt < 4; jt++) {
            int col = nB + jt * 16 + l15;
            float bcol = bias[col];
#pragma unroll
            for (int reg = 0; reg < 4; reg++) {
                int rr = rbase + reg;
                if (rr < M) {
                    float vv = acc[jt][reg] + bcol;
                    if (EPI == 1) vv = 0.5f * vv * (1.f + erff(vv * 0.70710678118654752f));
                    if (EPI == 2) {
                        vv += res[(size_t)rr * N + col];
                        if (res2) vv += res2[(size_t)rr * N + col];
                    }
                    if (WF32) C[(size_t)rr * N + col] = vv;
                    if (WBF)  C2[(size_t)rr * N + col] = f2bf(vv);
                }
            }
        }
    }
}

// ---------------------------------------------------------------------------
// MFMA attention — byte-identical to the R7/R10-passing version (frozen).
// P in registers via kappa-permuted swapped QK^T; Z on the MFMA pipe
// (ones-fragment).  Single LDS buffer, two barriers per chunk.
// ---------------------------------------------------------------------------
#define TQA 64
#define CH 64
#define VSTR 72

__global__ __launch_bounds__(256) void attn_mfma(
    const short* __restrict__ qf, const short* __restrict__ kf,
    const short* __restrict__ vf, short* __restrict__ attn_out,
    float* __restrict__ Zp)
{
    const int qt  = blockIdx.x;
    const int bm  = blockIdx.y;
    const int cam = blockIdx.z;
    const int b = bm >> 3, m = bm & 7;
    const int q0 = qt * TQA;
    const int tid = threadIdx.x;
    const int w = tid >> 6, lane = tid & 63;
    const int l15 = lane & 15, quad = lane >> 4;

    __shared__ __align__(16) short Ks[CH][DH];
    __shared__ __align__(16) short Vt[DH][VSTR];

    const size_t slab = (size_t)(b * 6 + cam);

    int qrow = q0 + w * 16 + l15;
    int qcl  = qrow < HW ? qrow : HW - 1;
    const short8 aq = *(const short8*)&qf[(slab * HW + qcl) * DIM + m * DH + quad * 8];

    const short* kb = kf + slab * KP * DIM + m * DH;
    const short* vb = vf + slab * KP * DIM + m * DH;

    f32x4 oacc[2];
    oacc[0] = (f32x4){0.f, 0.f, 0.f, 0.f};
    oacc[1] = (f32x4){0.f, 0.f, 0.f, 0.f};
    f32x4 zacc = (f32x4){0.f, 0.f, 0.f, 0.f};
    const short one_bf = (short)0x3F80;                 // bf16 1.0
    const short8 ones8 = {one_bf, one_bf, one_bf, one_bf,
                          one_bf, one_bf, one_bf, one_bf};

    // K staging: one b128 per thread, kappa-permuted destination row
    const int kl = tid >> 2, d8 = (tid & 3) * 8;
    const int jtw  = ((kl >> 5) & 1) | (((kl >> 2) & 1) << 1);
    const int rw   = (((kl >> 3) & 3) << 2) | (kl & 3);
    const int krow = jtw * 16 + rw;
    // V pair staging: two adjacent keys, 4 dh each -> 4 ds_write_b32
    const int kp2 = tid >> 3, dv = (tid & 7) * 4;
    const int vcol2 = (((kp2 >> 2) ^ (dv >> 3)) << 3) | ((2 * kp2) & 7);

    for (int c0 = 0; c0 < KP; c0 += CH) {
        __syncthreads();
        {
            int key = c0 + kl;
            short8 kv8 = {0, 0, 0, 0, 0, 0, 0, 0};
            if (key < KP) kv8 = *(const short8*)&kb[(size_t)key * DIM + d8];
            *(short8*)&Ks[krow][d8] = kv8;

            int k0v = c0 + 2 * kp2;
            uint2 a0 = {0u, 0u}, a1 = {0u, 0u};
            if (k0v < KP)     a0 = *(const uint2*)&vb[(size_t)k0v * DIM + dv];
            if (k0v + 1 < KP) a1 = *(const uint2*)&vb[(size_t)(k0v + 1) * DIM + dv];
            // interleave keys: (v0[t] | v1[t]<<16) via v_perm_b32
            *(unsigned*)&Vt[dv + 0][vcol2] = __builtin_amdgcn_perm(a1.x, a0.x, 0x05040100u);
            *(unsigned*)&Vt[dv + 1][vcol2] = __builtin_amdgcn_perm(a1.x, a0.x, 0x07060302u);
            *(unsigned*)&Vt[dv + 2][vcol2] = __builtin_amdgcn_perm(a1.y, a0.y, 0x05040100u);
            *(unsigned*)&Vt[dv + 3][vcol2] = __builtin_amdgcn_perm(a1.y, a0.y, 0x07060302u);
        }
        __syncthreads();
        // swapped QK^T over kappa-permuted K rows
        f32x4 sfragT[4];
#pragma unroll
        for (int jt = 0; jt < 4; jt++) {
            short8 bk8 = *(const short8*)&Ks[jt * 16 + l15][quad * 8];
            sfragT[jt] = __builtin_amdgcn_mfma_f32_16x16x32_bf16(
                bk8, aq, (f32x4){0.f, 0.f, 0.f, 0.f}, 0, 0, 0);
        }
        // softmax numerator -> in-register PV A-fragments
        union PA { unsigned u[4]; short8 s8; } pa[2];
        if (c0 + CH <= KP) {   // full chunk (0..8): no key masking
#pragma unroll
            for (int jt = 0; jt < 4; jt++) {
                float e0 = exp2_hw(sfragT[jt][0]);
                float e1 = exp2_hw(sfragT[jt][1]);
                float e2 = exp2_hw(sfragT[jt][2]);
                float e3 = exp2_hw(sfragT[jt][3]);
                asm("v_cvt_pk_bf16_f32 %0, %1, %2"
                    : "=v"(pa[jt & 1].u[(jt >> 1) * 2]) : "v"(e0), "v"(e1));
                asm("v_cvt_pk_bf16_f32 %0, %1, %2"
                    : "=v"(pa[jt & 1].u[(jt >> 1) * 2 + 1]) : "v"(e2), "v"(e3));
            }
        } else {               // tail chunk: mask keys >= KP
            int kq8 = c0 + quad * 8;
#pragma unroll
            for (int jt = 0; jt < 4; jt++) {
                int kb0 = kq8 + (jt & 1) * 32 + ((jt >> 1) << 2);
                float e0 = (kb0 + 0 < KP) ? exp2_hw(sfragT[jt][0]) : 0.f;
                float e1 = (kb0 + 1 < KP) ? exp2_hw(sfragT[jt][1]) : 0.f;
                float e2 = (kb0 + 2 < KP) ? exp2_hw(sfragT[jt][2]) : 0.f;
                float e3 = (kb0 + 3 < KP) ? exp2_hw(sfragT[jt][3]) : 0.f;
                asm("v_cvt_pk_bf16_f32 %0, %1, %2"
                    : "=v"(pa[jt & 1].u[(jt >> 1) * 2]) : "v"(e0), "v"(e1));
                asm("v_cvt_pk_bf16_f32 %0, %1, %2"
                    : "=v"(pa[jt & 1].u[(jt >> 1) * 2 + 1]) : "v"(e2), "v"(e3));
            }
        }
        // PV: A-fragment direct from registers; Z rides the MFMA pipe
#pragma unroll
        for (int ks = 0; ks < 2; ks++) {
#pragma unroll
            for (int nt = 0; nt < 2; nt++) {
                int dhn = nt * 16 + l15;
                int pgrp = ((ks * 4 + quad) ^ (dhn >> 3));
                short8 bv8 = *(const short8*)&Vt[dhn][pgrp << 3];
                oacc[nt] = __builtin_amdgcn_mfma_f32_16x16x32_bf16(
                    pa[ks].s8, bv8, oacc[nt], 0, 0, 0);
            }
            zacc = __builtin_amdgcn_mfma_f32_16x16x32_bf16(
                pa[ks].s8, ones8, zacc, 0, 0, 0);
        }
    }
    // zacc rows = q (quad*4+reg); all 16 cols identical -> write from l15==0
    if (l15 == 0) {
#pragma unroll
        for (int reg = 0; reg < 4; reg++) {
            int q = q0 + w * 16 + quad * 4 + reg;
            if (q < HW) Zp[((size_t)bm * 6 + cam) * HW + q] = zacc[reg];
        }
    }
#pragma unroll
    for (int reg = 0; reg < 4; reg++) {
        int q = q0 + w * 16 + quad * 4 + reg;
        if (q < HW) {
            size_t rowb = ((size_t)b * HW + q) * NDIM + cam * DIM + m * DH;
            attn_out[rowb + l15]      = f2bf(oacc[0][reg]);
            attn_out[rowb + 16 + l15] = f2bf(oacc[1][reg]);
        }
    }
}

// ---------------------------------------------------------------------------
// LayerNorm over 1536 (bf16 in) + fused joint-softmax normalization -> bf16.
// ---------------------------------------------------------------------------
__global__ __launch_bounds__(256) void ln_pre_kernel(
    const short* __restrict__ xin, short* __restrict__ lnbf,
    const float* __restrict__ Zp,
    const float* __restrict__ g, const float* __restrict__ bt)
{
    const int row = blockIdx.x;
    const int tid = threadIdx.x;
    const int b = row / 2500, q = row % 2500;
    __shared__ float zinv[8];
    if (tid < 8) {
        float z = 0.f;
#pragma unroll
        for (int cam = 0; cam < 6; cam++)
            z += Zp[((size_t)(b * 8 + tid) * 6 + cam) * HW + q];
        zinv[tid] = 1.f / z;
    }
    __syncthreads();
    const short* p = xin + (size_t)row * NDIM;
    float v[6];
    float s = 0.f, ss = 0.f;
#pragma unroll
    for (int i = 0; i < 6; i++) {
        int c = tid + i * 256;
        v[i] = bf2f(p[c]) * zinv[(c >> 5) & 7];
        s += v[i]; ss += v[i] * v[i];
    }
    __shared__ float rs[4], rss[4];
    int lane = tid & 63, wid = tid >> 6;
#pragma unroll
    for (int o = 32; o > 0; o >>= 1) { s += __shfl_down(s, o); ss += __shfl_down(ss, o); }
    if (lane == 0) { rs[wid] = s; rss[wid] = ss; }
    __syncthreads();
    s = rs[0] + rs[1] + rs[2] + rs[3];
    ss = rss[0] + rss[1] + rss[2] + rss[3];
    float mu = s * (1.f / NDIM);
    float var = ss * (1.f / NDIM) - mu * mu;
    float inv = rsqrtf(var + 1e-5f);
#pragma unroll
    for (int i = 0; i < 6; i++) {
        int c = tid + i * 256;
        lnbf[(size_t)row * NDIM + c] = f2bf((v[i] - mu) * inv * g[c] + bt[c]);
    }
}

// ---------------------------------------------------------------------------
// final2 (as R7): coalesced transpose store.
// ---------------------------------------------------------------------------
__global__ __launch_bounds__(256) void final_kernel2(
    const float* __restrict__ x, const float* __restrict__ y2,
    const float* __restrict__ g, const float* __restrict__ bt,
    float* __restrict__ out)
{
    __shared__ float T[256][33];
    __shared__ float ps[32][8], pss[32][8];
    __shared__ float mu_s[32], inv_s[32];
    const int tid = threadIdx.x;
    const int rl = tid & 31, seg = tid >> 5;
    const int r0 = blockIdx.x * 32;
    const int row = r0 + rl;
    const bool ok = row < 5000;

    float4 yv[8];
    float s = 0.f, ss = 0.f;
    if (ok) {
        const float4* yp = (const float4*)(y2 + (size_t)row * DIM + seg * 32);
#pragma unroll
        for (int j = 0; j < 8; j++) {
            yv[j] = yp[j];
            s += yv[j].x + yv[j].y + yv[j].z + yv[j].w;
            ss += yv[j].x * yv[j].x + yv[j].y * yv[j].y
                + yv[j].z * yv[j].z + yv[j].w * yv[j].w;
        }
    } else {
#pragma unroll
        for (int j = 0; j < 8; j++) yv[j] = (float4){0, 0, 0, 0};
    }
    ps[rl][seg] = s; pss[rl][seg] = ss;
    __syncthreads();
    if (tid < 32) {
        float a = 0.f, b2 = 0.f;
#pragma unroll
        for (int j = 0; j < 8; j++) { a += ps[tid][j]; b2 += pss[tid][j]; }
        float mu = a * (1.f / DIM);
        float var = b2 * (1.f / DIM) - mu * mu;
        mu_s[tid] = mu;
        inv_s[tid] = rsqrtf(var + 1e-5f);
    }
    __syncthreads();
    if (ok) {
        float mu = mu_s[rl], inv = inv_s[rl];
        const float4* xp = (const float4*)(x + (size_t)row * DIM + seg * 32);
#pragma unroll
        for (int j = 0; j < 8; j++) {
            float4 xv = xp[j];
            int c = seg * 32 + j * 4;
            T[c + 0][rl] = xv.x + (yv[j].x - mu) * inv * g[c + 0] + bt[c + 0];
            T[c + 1][rl] = xv.y + (yv[j].y - mu) * inv * g[c + 1] + bt[c + 1];
            T[c + 2][rl] = xv.z + (yv[j].z - mu) * inv * g[c + 2] + bt[c + 2];
            T[c + 3][rl] = xv.w + (yv[j].w - mu) * inv * g[c + 3] + bt[c + 3];
        }
    }
    __syncthreads();
    const int w = tid >> 6, lane = tid & 63;
    const int hl = lane & 31, ch = lane >> 5;
    const int rr = r0 + hl;
    if (rr < 5000) {
        int b = rr / 2500, hw = rr % 2500;
        size_t obase = (size_t)b * 640000 + hw;
#pragma unroll
        for (int it = 0; it < 32; it++) {
            int c = it * 8 + w * 2 + ch;
            out[obase + (size_t)c * 2500] = T[c][hl];
        }
    }
}

// ---------------------------------------------------------------------------
extern "C" void kernel_launch(void* const* d_in, const int* in_sizes, int n_in,
                              void* d_out, int out_size, void* d_ws, size_t ws_size,
                              hipStream_t stream)
{
    const float* q     = (const float*)d_in[0];
    const float* k     = (const float*)d_in[1];
    const float* v     = (const float*)d_in[2];
    const float* Wq    = (const float*)d_in[3];
    const float* bq    = (const float*)d_in[4];
    const float* Wk    = (const float*)d_in[5];
    const float* bk    = (const float*)d_in[6];
    const float* Wv    = (const float*)d_in[7];
    const float* bv    = (const float*)d_in[8];
    const float* Wproj = (const float*)d_in[9];
    const float* bproj = (const float*)d_in[10];
    const float* Waddq = (const float*)d_in[11];
    const float* baddq = (const float*)d_in[12];
    const float* W1    = (const float*)d_in[13];
    const float* b1    = (const float*)d_in[14];
    const float* W2    = (const float*)d_in[15];
    const float* b2    = (const float*)d_in[16];
    const float* g_pre = (const float*)d_in[17];
    const float* b_pre = (const float*)d_in[18];
    const float* g_nrm = (const float*)d_in[19];
    const float* b_nrm = (const float*)d_in[20];
    float* out = (float*)d_out;

    // workspace layout (float-unit offsets)
    float* ws = (float*)d_ws;
    short* qf_a   = (short*)(ws);             // [0, 3.84M)
    short* lnbf   = (short*)(ws);             //   alias after attn
    short* qbf    = (short*)(ws + 3840000);   // [3.84M, 7.68M)
    short* kf_a   = (short*)(ws + 7680000);   // [7.68M, 8.64M)
    short* kpbf   = (short*)(ws + 8640000);   // [8.64M, 9.6M)
    short* vf_a   = (short*)(ws + 9600000);   // [9.6M, 10.56M)
    short* vpbf   = (short*)(ws + 10560000);  // [10.56M, 11.52M)
    float* add_q  = ws + 11520000;            // [11.52M, 12.8M)
    short* attn_o = (short*)(ws + 12800000);  // bf16: [12.8M, 16.64M)
    short* xbf    = (short*)(ws + 12800000);  //   alias: live only after ln_pre
    short* h1bf   = (short*)(ws + 13440000);  //   alias: [13.44M, 14.72M)
    float* add_q2 = ws + 16640000;            // [16.64M, 17.92M) split-K partial
    float* x      = ws + 20480000;            // [20.48M, 21.76M)
    float* Zp     = ws + 21760000;            // [21.76M, 22M)
    short* eW     = (short*)(ws + 22000000);
    short* Wq_t    = eW;
    short* Wk_t    = eW + 65536;
    short* Wv_t    = eW + 131072;
    short* Waddq_t = eW + 196608;
    short* lW     = (short*)(ws + 22295000);
    short* Wproj_t = lW;
    short* W1_t    = lW + 393216;
    short* W2_t    = lW + 524288;
    float* y2     = ws + 22625000;            // [22.62M, 23.9M)

    dim3 blk(256);

    // 1) all conversion work in one launch
    {
        WArgs wa;
        wa.j[0] = {Wq,    Wq_t,    256,  256};
        wa.j[1] = {Wk,    Wk_t,    256,  256};
        wa.j[2] = {Wv,    Wv_t,    256,  256};
        wa.j[3] = {Waddq, Waddq_t, 1536, 256};
        wa.j[4] = {Wproj, Wproj_t, 1536, 256};
        wa.j[5] = {W1,    W1_t,    256,  512};
        wa.j[6] = {W2,    W2_t,    512,  256};
        prep_all<<<dim3(12640), blk, 0, stream>>>(q, k, v, qbf, kpbf, vpbf, wa);
    }
    // 2) all input-side GEMMs, flat grid: long add_q blocks first (HW
    //    round-robin spreads them across XCDs) + split-K(2x768)
    //    qf job pre-scales by softmax scale * log2e (consumed only by attn)
    {
        GArgs ga;
        //          A     Bt       bias     Cb       Cf      M      Ks    Kl   kOff mode smul
        ga.j[0] = {qbf,  Waddq_t, baddq,   nullptr, add_q,  5000,  1536, 768, 0,   1, 1.0f};
        ga.j[1] = {qbf,  Waddq_t, nullptr, nullptr, add_q2, 5000,  1536, 768, 768, 1, 1.0f};
        ga.j[2] = {qbf,  Wq_t,    bq,      qf_a,    nullptr, 30000, 256, 256, 0,   0, SCALE_LOG2E};
        ga.j[3] = {kpbf, Wk_t,    bk,      kf_a,    nullptr, 7500,  256, 256, 0,   0, 1.0f};
        ga.j[4] = {vpbf, Wv_t,    bv,      vf_a,    nullptr, 7500,  256, 256, 0,   0, 1.0f};
        int cnt[5] = {160, 160, 940, 236, 236};   // 40*4, 40*4, 235*4, 59*4, 59*4
        ga.base[0] = 0;
        for (int i = 0; i < 5; i++) ga.base[i + 1] = ga.base[i] + cnt[i];
        gemm_in<<<dim3(ga.base[5]), blk, 0, stream>>>(ga);
    }
    // 3) attention (bf16 out, P in registers, Z on MFMA pipe) — frozen R7 form
    attn_mfma<<<dim3(40, 16, 6), blk, 0, stream>>>(qf_a, kf_a, vf_a, attn_o, Zp);
    // 4) LN(1536) + softmax-normalize -> bf16 (into dead qf_a region)
    ln_pre_kernel<<<dim3(5000), blk, 0, stream>>>(attn_o, lnbf, Zp, g_pre, b_pre);
    // 5) x = ln @ Wproj + bproj + add_q + add_q2  (fp32 x + bf16 xbf), BM=64
    mgemm64<2, 1, 1><<<dim3(4, 79), blk, 0, stream>>>(
        lnbf, Wproj_t, bproj, add_q, add_q2, x, xbf, 5000, 256, 1536);
    // 6) h1 = gelu(x @ W1 + b1) -> bf16, BM=64
    mgemm64<1, 0, 1><<<dim3(8, 79), blk, 0, stream>>>(
        xbf, W1_t, b1, nullptr, nullptr, nullptr, h1bf, 5000, 512, 256);
    // 7) y2 = h1 @ W2 + b2 -> fp32, BM=64
    mgemm64<0, 1, 0><<<dim3(4, 79), blk, 0, stream>>>(
        h1bf, W2_t, b2, nullptr, nullptr, y2, nullptr, 5000, 256, 512);
    // 8) out = transpose(x + LN256(y2)) — coalesced
    final_kernel2<<<dim3(157), blk, 0, stream>>>(x, y2, g_nrm, b_nrm, out);
}

// Round 13
// 302.933 us; speedup vs baseline: 1.0505x; 1.0099x over previous
//
#include <hip/hip_runtime.h>
#include <math.h>

// Problem constants
#define BATCH 2
#define NCAM 6
#define DIM 256
#define HEADS 8
#define DH 32
#define HW 2500          // 50*50
#define KP 625           // 25*25 pooled keys per cam
#define NDIM (NCAM*DIM)  // 1536

// scale/sqrt(dh) folded with log2(e) into the qf GEMM epilogue:
// 1.4426950408889634 / sqrt(32) = 0.25503488494404
#define SCALE_LOG2E 0.25503488494404f

typedef __attribute__((ext_vector_type(8))) short short8;
typedef __attribute__((ext_vector_type(4))) float f32x4;

__device__ __forceinline__ short f2bf(float f) {
    union { float f; unsigned u; } v; v.f = f;
    unsigned r = v.u + 0x7fffu + ((v.u >> 16) & 1u);   // round-to-nearest-even
    return (short)(r >> 16);
}
__device__ __forceinline__ float bf2f(short h) {
    union { unsigned u; float f; } v; v.u = ((unsigned)(unsigned short)h) << 16;
    return v.f;
}
// 2^x via the HW base-2 exp instruction
__device__ __forceinline__ float exp2_hw(float x) {
    return __builtin_amdgcn_exp2f(x);
}

// ---------------------------------------------------------------------------
// prep_all: ALL one-time data conversion in ONE launch (as R7).
// ---------------------------------------------------------------------------
struct WJ { const float* src; short* dst; int K, N; };
struct WArgs { WJ j[7]; };

__global__ __launch_bounds__(256) void prep_all(
    const float* __restrict__ q, const float* __restrict__ k,
    const float* __restrict__ v, short* __restrict__ qbf,
    short* __restrict__ kpbf, short* __restrict__ vpbf, WArgs wa)
{
    __shared__ float t[32][33];
    const int tx = threadIdx.x & 31, ty = threadIdx.x >> 5;   // ty 0..7
    int i = blockIdx.x;
    if (i < 7584) {
        int slab = i / 632, rem = i % 632;
        int hwB = (rem % 79) * 32, dB = (rem / 79) * 32;
        const float* src = q + (size_t)slab * 640000;
#pragma unroll
        for (int ii = 0; ii < 32; ii += 8) {
            int hw = hwB + tx;
            t[ty + ii][tx] = (hw < HW) ? src[(size_t)(dB + ty + ii) * HW + hw] : 0.f;
        }
        __syncthreads();
#pragma unroll
        for (int ii = 0; ii < 32; ii += 8) {
            int hw = hwB + ty + ii;
            if (hw < HW)
                qbf[((size_t)slab * HW + hw) * DIM + dB + tx] = f2bf(t[tx][ty + ii]);
        }
    } else if (i < 11424) {
        int i2 = i - 7584;
        const float* base; short* dst;
        if (i2 < 1920) { base = k; dst = kpbf; }
        else           { base = v; dst = vpbf; i2 -= 1920; }
        int slab = i2 / 160, rem = i2 % 160;
        int kpB = (rem % 20) * 32, dB = (rem / 20) * 32;
        const float* src = base + (size_t)slab * 640000;
        dst += (size_t)slab * (KP * DIM);
#pragma unroll
        for (int ii = 0; ii < 32; ii += 8) {
            int kp = kpB + tx;
            float val = 0.f;
            if (kp < KP) {
                int r2 = (kp / 25) * 2, c2 = (kp % 25) * 2;
                const float* p0 = src + (size_t)(dB + ty + ii) * HW + r2 * 50 + c2;
                val = 0.25f * (p0[0] + p0[1] + p0[50] + p0[51]);
            }
            t[ty + ii][tx] = val;
        }
        __syncthreads();
#pragma unroll
        for (int ii = 0; ii < 32; ii += 8) {
            int kp = kpB + ty + ii;
            if (kp < KP)
                dst[(size_t)kp * DIM + dB + tx] = f2bf(t[tx][ty + ii]);
        }
    } else {
        int wi = i - 11424;
        WJ jb = wa.j[0];
        for (int jj = 0; jj < 7; jj++) {
            jb = wa.j[jj];
            int cnt = (jb.K >> 5) * (jb.N >> 5);
            if (wi < cnt) break;
            wi -= cnt;
        }
        int tn = jb.N >> 5;
        int nB = (wi % tn) * 32, kB = (wi / tn) * 32;
#pragma unroll
        for (int ii = 0; ii < 32; ii += 8)
            t[ty + ii][tx] = jb.src[(size_t)(kB + ty + ii) * jb.N + nB + tx];
        __syncthreads();
#pragma unroll
        for (int ii = 0; ii < 32; ii += 8)
            jb.dst[(size_t)(nB + ty + ii) * jb.K + kB + tx] = f2bf(t[tx][ty + ii]);
    }
}

// ---------------------------------------------------------------------------
// Batched input GEMMs (R6-proven): flat 1D grid, add_q split-K (2x768),
// LDS double-buffer, ONE barrier per K-tile, write-early staging.
// ---------------------------------------------------------------------------
struct GJob { const short* A; const short* Bt; const float* bias;
              short* Cb; float* Cf; int M, Ks, Kl, kOff, mode; float smul; };
struct GArgs { GJob j[5]; int base[6]; };

__global__ __launch_bounds__(256) void gemm_in(GArgs ga) {
    int bid = blockIdx.x;
    int jj = 0;
    while (bid >= ga.base[jj + 1]) jj++;
    GJob jb = ga.j[jj];
    const int local = bid - ga.base[jj];

    __shared__ short As[2][128 * 32];
    __shared__ short Bs[2][64 * 32];

    const int tid  = threadIdx.x;
    const int nB   = (local & 3) * 64;
    const int rB   = (local >> 2) * 128;
    const int w    = tid >> 6;
    const int lane = tid & 63;
    const int l15  = lane & 15;
    const int quad = lane >> 4;
    const int M = jb.M, Ks = jb.Ks, kOff = jb.kOff;
    const int nT = jb.Kl >> 5;

    f32x4 acc[2][4];
#pragma unroll
    for (int i = 0; i < 2; i++)
#pragma unroll
        for (int jt = 0; jt < 4; jt++) acc[i][jt] = (f32x4){0.f, 0.f, 0.f, 0.f};

    const int ra = tid >> 1, k0 = (tid & 1) * 16;   // A staging
    const int rga = rB + ra;
    const int bb = rga / 2500, hwp = rga % 2500;    // mode 1 row decode
    const int nb_ = tid >> 2, gkb = tid & 3;        // B staging
    const int g0 = k0 >> 3;

    short8 pa0 = {0,0,0,0,0,0,0,0}, pa1 = pa0, pb = pa0;

#define GLOADT(t) do {                                                        \
        int kk = kOff + (t) * 32 + k0;                                        \
        if (rga < M) {                                                        \
            const short* p;                                                   \
            if (jb.mode) {                                                    \
                int cam = kk >> 8, c = kk & 255;                              \
                p = &jb.A[(((size_t)(bb * 6 + cam)) * HW + hwp) * DIM + c];   \
            } else {                                                          \
                p = &jb.A[(size_t)rga * Ks + kk];                             \
            }                                                                 \
            pa0 = *(const short8*)p; pa1 = *(const short8*)(p + 8);           \
        }                                                                     \
        pb = *(const short8*)&jb.Bt[(size_t)(nB + nb_) * Ks                   \
                                    + kOff + (t) * 32 + gkb * 8];             \
    } while (0)

#define STAGET(bf) do {                                                       \
        *(short8*)&As[bf][ra * 32 + ((g0 ^ (ra & 3)) << 3)]       = pa0;      \
        *(short8*)&As[bf][ra * 32 + (((g0 + 1) ^ (ra & 3)) << 3)] = pa1;      \
        *(short8*)&Bs[bf][nb_ * 32 + ((gkb ^ (nb_ & 3)) << 3)]    = pb;       \
    } while (0)

    // prologue: tile 0 -> buf0; issue tile 1 loads
    GLOADT(0);
    STAGET(0);
    if (nT > 1) GLOADT(1);
    __syncthreads();

    int cur = 0;
    for (int t = 0; t < nT; t++) {
        if (t + 1 < nT) STAGET(cur ^ 1);
        if (t + 2 < nT) GLOADT(t + 2);
        short8 af[2], bfr[4];
#pragma unroll
        for (int i = 0; i < 2; i++) {
            int m = w * 32 + i * 16 + l15;
            af[i] = *(const short8*)&As[cur][m * 32 + ((quad ^ (m & 3)) << 3)];
        }
#pragma unroll
        for (int jt = 0; jt < 4; jt++) {
            int n = jt * 16 + l15;
            bfr[jt] = *(const short8*)&Bs[cur][n * 32 + ((quad ^ (n & 3)) << 3)];
        }
#pragma unroll
        for (int i = 0; i < 2; i++)
#pragma unroll
            for (int jt = 0; jt < 4; jt++)
                acc[i][jt] = __builtin_amdgcn_mfma_f32_16x16x32_bf16(
                    af[i], bfr[jt], acc[i][jt], 0, 0, 0);
        if (t + 1 < nT) { __syncthreads(); cur ^= 1; }
    }
#undef GLOADT
#undef STAGET

#pragma unroll
    for (int i = 0; i < 2; i++) {
        int rbase = rB + w * 32 + i * 16 + quad * 4;
#pragma unroll
        for (int jt = 0; jt < 4; jt++) {
            int col = nB + jt * 16 + l15;
            float bcol = jb.bias ? jb.bias[col] : 0.f;
#pragma unroll
            for (int reg = 0; reg < 4; reg++) {
                int rr = rbase + reg;
                if (rr < M) {
                    float vv = (acc[i][jt][reg] + bcol) * jb.smul;
                    if (jb.Cb) jb.Cb[(size_t)rr * 256 + col] = f2bf(vv);
                    else       jb.Cf[(size_t)rr * 256 + col] = vv;
                }
            }
        }
    }
}

// ---------------------------------------------------------------------------
// Tail GEMM (R12-proven): BM=64, single-barrier write-early LDS dbuf.
// EPI 0: bias; 1: bias+GELU; 2: bias+res(+res2).  WF32: fp32 C; WBF: bf16 C2.
// ---------------------------------------------------------------------------
template<int EPI, int WF32, int WBF>
__global__ __launch_bounds__(256) void mgemm64(
    const short* __restrict__ A, const short* __restrict__ Bt,
    const float* __restrict__ bias, const float* __restrict__ res,
    const float* __restrict__ res2,
    float* __restrict__ C, short* __restrict__ C2, int M, int N, int K)
{
    __shared__ short As[2][64 * 32];
    __shared__ short Bs[2][64 * 32];

    const int tid  = threadIdx.x;
    const int nB   = blockIdx.x * 64;
    const int rB   = blockIdx.y * 64;
    const int w    = tid >> 6;
    const int lane = tid & 63;
    const int l15  = lane & 15;
    const int quad = lane >> 4;
    const int nT   = K >> 5;

    f32x4 acc[4];
#pragma unroll
    for (int jt = 0; jt < 4; jt++) acc[jt] = (f32x4){0.f, 0.f, 0.f, 0.f};

    const int ra4 = tid >> 2, ga = tid & 3;     // A staging: 1 short8/thread
    const int ka  = ga * 8;
    const int rga = rB + ra4;
    const int nb_ = tid >> 2, gkb = tid & 3;    // B staging

    short8 pa0 = {0,0,0,0,0,0,0,0}, pb = pa0;

#define MGLOAD(t) do {                                                        \
        if (rga < M)                                                          \
            pa0 = *(const short8*)&A[(size_t)rga * K + (t) * 32 + ka];        \
        pb = *(const short8*)&Bt[(size_t)(nB + nb_) * K + (t) * 32 + gkb * 8];\
    } while (0)

#define MSTAGE(bf) do {                                                       \
        *(short8*)&As[bf][ra4 * 32 + ((ga ^ (ra4 & 3)) << 3)] = pa0;          \
        *(short8*)&Bs[bf][nb_ * 32 + ((gkb ^ (nb_ & 3)) << 3)] = pb;          \
    } while (0)

    MGLOAD(0);
    MSTAGE(0);
    if (nT > 1) MGLOAD(1);
    __syncthreads();

    int cur = 0;
    for (int t = 0; t < nT; t++) {
        if (t + 1 < nT) MSTAGE(cur ^ 1);
        if (t + 2 < nT) MGLOAD(t + 2);
        short8 af, bfr[4];
        {
            int m = w * 16 + l15;
            af = *(const short8*)&As[cur][m * 32 + ((quad ^ (m & 3)) << 3)];
        }
#pragma unroll
        for (int jt = 0; jt < 4; jt++) {
            int n = jt * 16 + l15;
            bfr[jt] = *(const short8*)&Bs[cur][n * 32 + ((quad ^ (n & 3)) << 3)];
        }
#pragma unroll
        for (int jt = 0; jt < 4; jt++)
            acc[jt] = __builtin_amdgcn_mfma_f32_16x16x32_bf16(
                af, bfr[jt], acc[jt], 0, 0, 0);
        if (t + 1 < nT) { __syncthreads(); cur ^= 1; }
    }
#undef MGLOAD
#undef MSTAGE

    {
        int rbase = rB + w * 16 + quad * 4;
#pragma unroll
        for (int jt = 0; jt < 4; jt++) {
            int col = nB + jt * 16 + l15;
            float bcol = bias[col];
#pragma unroll
            for (int reg = 0; reg < 4; reg++) {
                int rr = rbase + reg;
                if (rr < M) {
                    float vv = acc[jt][reg] + bcol;
                    if (EPI == 1) vv = 0.5f * vv * (1.f + erff(vv * 0.70710678118654752f));
                    if (EPI == 2) {
                        vv += res[(size_t)rr * N + col];
                        if (res2) vv += res2[(size_t)rr * N + col];
                    }
                    if (WF32) C[(size_t)rr * N + col] = vv;
                    if (WBF)  C2[(size_t)rr * N + col] = f2bf(vv);
                }
            }
        }
    }
}

// ---------------------------------------------------------------------------
// MFMA attention, R13: TQA=128 — two q-row groups per block share each
// staged K/V chunk.  Staging, barriers and chunk loop are byte-identical to
// the frozen R7 form; only the compute section is doubled, with K- and
// V-fragments read from LDS ONCE and feeding both groups' MFMAs.  Per unit
// work: barriers x1/2, K/V fetch x1/2, LDS reads x1/2.  P in registers,
// Z on the MFMA pipe.
// ---------------------------------------------------------------------------
#define TQA 128
#define CH 64
#define VSTR 72

__global__ __launch_bounds__(256) void attn_mfma(
    const short* __restrict__ qf, const short* __restrict__ kf,
    const short* __restrict__ vf, short* __restrict__ attn_out,
    float* __restrict__ Zp)
{
    const int qt  = blockIdx.x;
    const int bm  = blockIdx.y;
    const int cam = blockIdx.z;
    const int b = bm >> 3, m = bm & 7;
    const int q0 = qt * TQA;
    const int tid = threadIdx.x;
    const int w = tid >> 6, lane = tid & 63;
    const int l15 = lane & 15, quad = lane >> 4;

    __shared__ __align__(16) short Ks[CH][DH];
    __shared__ __align__(16) short Vt[DH][VSTR];

    const size_t slab = (size_t)(b * 6 + cam);

    short8 aq[2];
#pragma unroll
    for (int g = 0; g < 2; g++) {
        int qrow = q0 + g * 64 + w * 16 + l15;
        int qcl  = qrow < HW ? qrow : HW - 1;
        aq[g] = *(const short8*)&qf[(slab * HW + qcl) * DIM + m * DH + quad * 8];
    }

    const short* kb = kf + slab * KP * DIM + m * DH;
    const short* vb = vf + slab * KP * DIM + m * DH;

    f32x4 oacc[2][2];
    f32x4 zacc[2];
#pragma unroll
    for (int g = 0; g < 2; g++) {
        oacc[g][0] = (f32x4){0.f, 0.f, 0.f, 0.f};
        oacc[g][1] = (f32x4){0.f, 0.f, 0.f, 0.f};
        zacc[g]    = (f32x4){0.f, 0.f, 0.f, 0.f};
    }
    const short one_bf = (short)0x3F80;                 // bf16 1.0
    const short8 ones8 = {one_bf, one_bf, one_bf, one_bf,
                          one_bf, one_bf, one_bf, one_bf};

    // K staging: one b128 per thread, kappa-permuted destination row
    const int kl = tid >> 2, d8 = (tid & 3) * 8;
    const int jtw  = ((kl >> 5) & 1) | (((kl >> 2) & 1) << 1);
    const int rw   = (((kl >> 3) & 3) << 2) | (kl & 3);
    const int krow = jtw * 16 + rw;
    // V pair staging: two adjacent keys, 4 dh each -> 4 ds_write_b32
    const int kp2 = tid >> 3, dv = (tid & 7) * 4;
    const int vcol2 = (((kp2 >> 2) ^ (dv >> 3)) << 3) | ((2 * kp2) & 7);

    for (int c0 = 0; c0 < KP; c0 += CH) {
        __syncthreads();
        {
            int key = c0 + kl;
            short8 kv8 = {0, 0, 0, 0, 0, 0, 0, 0};
            if (key < KP) kv8 = *(const short8*)&kb[(size_t)key * DIM + d8];
            *(short8*)&Ks[krow][d8] = kv8;

            int k0v = c0 + 2 * kp2;
            uint2 a0 = {0u, 0u}, a1 = {0u, 0u};
            if (k0v < KP)     a0 = *(const uint2*)&vb[(size_t)k0v * DIM + dv];
            if (k0v + 1 < KP) a1 = *(const uint2*)&vb[(size_t)(k0v + 1) * DIM + dv];
            // interleave keys: (v0[t] | v1[t]<<16) via v_perm_b32
            *(unsigned*)&Vt[dv + 0][vcol2] = __builtin_amdgcn_perm(a1.x, a0.x, 0x05040100u);
            *(unsigned*)&Vt[dv + 1][vcol2] = __builtin_amdgcn_perm(a1.x, a0.x, 0x07060302u);
            *(unsigned*)&Vt[dv + 2][vcol2] = __builtin_amdgcn_perm(a1.y, a0.y, 0x05040100u);
            *(unsigned*)&Vt[dv + 3][vcol2] = __builtin_amdgcn_perm(a1.y, a0.y, 0x07060302u);
        }
        __syncthreads();
        // swapped QK^T over kappa-permuted K rows; K-fragments shared by
        // both q-groups
        f32x4 sT[2][4];
#pragma unroll
        for (int jt = 0; jt < 4; jt++) {
            short8 bk8 = *(const short8*)&Ks[jt * 16 + l15][quad * 8];
            sT[0][jt] = __builtin_amdgcn_mfma_f32_16x16x32_bf16(
                bk8, aq[0], (f32x4){0.f, 0.f, 0.f, 0.f}, 0, 0, 0);
            sT[1][jt] = __builtin_amdgcn_mfma_f32_16x16x32_bf16(
                bk8, aq[1], (f32x4){0.f, 0.f, 0.f, 0.f}, 0, 0, 0);
        }
        // softmax numerator -> in-register PV A-fragments (both groups)
        union PA { unsigned u[4]; short8 s8; } pa[2][2];
        if (c0 + CH <= KP) {   // full chunk (0..8): no key masking
#pragma unroll
            for (int g = 0; g < 2; g++)
#pragma unroll
            for (int jt = 0; jt < 4; jt++) {
                float e0 = exp2_hw(sT[g][jt][0]);
                float e1 = exp2_hw(sT[g][jt][1]);
                float e2 = exp2_hw(sT[g][jt][2]);
                float e3 = exp2_hw(sT[g][jt][3]);
                asm("v_cvt_pk_bf16_f32 %0, %1, %2"
                    : "=v"(pa[g][jt & 1].u[(jt >> 1) * 2]) : "v"(e0), "v"(e1));
                asm("v_cvt_pk_bf16_f32 %0, %1, %2"
                    : "=v"(pa[g][jt & 1].u[(jt >> 1) * 2 + 1]) : "v"(e2), "v"(e3));
            }
        } else {               // tail chunk: mask keys >= KP
            int kq8 = c0 + quad * 8;
#pragma unroll
            for (int g = 0; g < 2; g++)
#pragma unroll
            for (int jt = 0; jt < 4; jt++) {
                int kb0 = kq8 + (jt & 1) * 32 + ((jt >> 1) << 2);
                float e0 = (kb0 + 0 < KP) ? exp2_hw(sT[g][jt][0]) : 0.f;
                float e1 = (kb0 + 1 < KP) ? exp2_hw(sT[g][jt][1]) : 0.f;
                float e2 = (kb0 + 2 < KP) ? exp2_hw(sT[g][jt][2]) : 0.f;
                float e3 = (kb0 + 3 < KP) ? exp2_hw(sT[g][jt][3]) : 0.f;
                asm("v_cvt_pk_bf16_f32 %0, %1, %2"
                    : "=v"(pa[g][jt & 1].u[(jt >> 1) * 2]) : "v"(e0), "v"(e1));
                asm("v_cvt_pk_bf16_f32 %0, %1, %2"
                    : "=v"(pa[g][jt & 1].u[(jt >> 1) * 2 + 1]) : "v"(e2), "v"(e3));
            }
        }
        // PV: V-fragments shared by both groups; Z rides the MFMA pipe
#pragma unroll
        for (int ks = 0; ks < 2; ks++) {
#pragma unroll
            for (int nt = 0; nt < 2; nt++) {
                int dhn = nt * 16 + l15;
                int pgrp = ((ks * 4 + quad) ^ (dhn >> 3));
                short8 bv8 = *(const short8*)&Vt[dhn][pgrp << 3];
                oacc[0][nt] = __builtin_amdgcn_mfma_f32_16x16x32_bf16(
                    pa[0][ks].s8, bv8, oacc[0][nt], 0, 0, 0);
                oacc[1][nt] = __builtin_amdgcn_mfma_f32_16x16x32_bf16(
                    pa[1][ks].s8, bv8, oacc[1][nt], 0, 0, 0);
            }
            zacc[0] = __builtin_amdgcn_mfma_f32_16x16x32_bf16(
                pa[0][ks].s8, ones8, zacc[0], 0, 0, 0);
            zacc[1] = __builtin_amdgcn_mfma_f32_16x16x32_bf16(
                pa[1][ks].s8, ones8, zacc[1], 0, 0, 0);
        }
    }
    // epilogue: both q-groups
#pragma unroll
    for (int g = 0; g < 2; g++) {
        if (l15 == 0) {
#pragma unroll
            for (int reg = 0; reg < 4; reg++) {
                int q = q0 + g * 64 + w * 16 + quad * 4 + reg;
                if (q < HW) Zp[((size_t)bm * 6 + cam) * HW + q] = zacc[g][reg];
            }
        }
#pragma unroll
        for (int reg = 0; reg < 4; reg++) {
            int q = q0 + g * 64 + w * 16 + quad * 4 + reg;
            if (q < HW) {
                size_t rowb = ((size_t)b * HW + q) * NDIM + cam * DIM + m * DH;
                attn_out[rowb + l15]      = f2bf(oacc[g][0][reg]);
                attn_out[rowb + 16 + l15] = f2bf(oacc[g][1][reg]);
            }
        }
    }
}

// ---------------------------------------------------------------------------
// LayerNorm over 1536 (bf16 in) + fused joint-softmax normalization -> bf16.
// ---------------------------------------------------------------------------
__global__ __launch_bounds__(256) void ln_pre_kernel(
    const short* __restrict__ xin, short* __restrict__ lnbf,
    const float* __restrict__ Zp,
    const float* __restrict__ g, const float* __restrict__ bt)
{
    const int row = blockIdx.x;
    const int tid = threadIdx.x;
    const int b = row / 2500, q = row % 2500;
    __shared__ float zinv[8];
    if (tid < 8) {
        float z = 0.f;
#pragma unroll
        for (int cam = 0; cam < 6; cam++)
            z += Zp[((size_t)(b * 8 + tid) * 6 + cam) * HW + q];
        zinv[tid] = 1.f / z;
    }
    __syncthreads();
    const short* p = xin + (size_t)row * NDIM;
    float v[6];
    float s = 0.f, ss = 0.f;
#pragma unroll
    for (int i = 0; i < 6; i++) {
        int c = tid + i * 256;
        v[i] = bf2f(p[c]) * zinv[(c >> 5) & 7];
        s += v[i]; ss += v[i] * v[i];
    }
    __shared__ float rs[4], rss[4];
    int lane = tid & 63, wid = tid >> 6;
#pragma unroll
    for (int o = 32; o > 0; o >>= 1) { s += __shfl_down(s, o); ss += __shfl_down(ss, o); }
    if (lane == 0) { rs[wid] = s; rss[wid] = ss; }
    __syncthreads();
    s = rs[0] + rs[1] + rs[2] + rs[3];
    ss = rss[0] + rss[1] + rss[2] + rss[3];
    float mu = s * (1.f / NDIM);
    float var = ss * (1.f / NDIM) - mu * mu;
    float inv = rsqrtf(var + 1e-5f);
#pragma unroll
    for (int i = 0; i < 6; i++) {
        int c = tid + i * 256;
        lnbf[(size_t)row * NDIM + c] = f2bf((v[i] - mu) * inv * g[c] + bt[c]);
    }
}

// ---------------------------------------------------------------------------
// final2 (as R7): coalesced transpose store.
// ---------------------------------------------------------------------------
__global__ __launch_bounds__(256) void final_kernel2(
    const float* __restrict__ x, const float* __restrict__ y2,
    const float* __restrict__ g, const float* __restrict__ bt,
    float* __restrict__ out)
{
    __shared__ float T[256][33];
    __shared__ float ps[32][8], pss[32][8];
    __shared__ float mu_s[32], inv_s[32];
    const int tid = threadIdx.x;
    const int rl = tid & 31, seg = tid >> 5;
    const int r0 = blockIdx.x * 32;
    const int row = r0 + rl;
    const bool ok = row < 5000;

    float4 yv[8];
    float s = 0.f, ss = 0.f;
    if (ok) {
        const float4* yp = (const float4*)(y2 + (size_t)row * DIM + seg * 32);
#pragma unroll
        for (int j = 0; j < 8; j++) {
            yv[j] = yp[j];
            s += yv[j].x + yv[j].y + yv[j].z + yv[j].w;
            ss += yv[j].x * yv[j].x + yv[j].y * yv[j].y
                + yv[j].z * yv[j].z + yv[j].w * yv[j].w;
        }
    } else {
#pragma unroll
        for (int j = 0; j < 8; j++) yv[j] = (float4){0, 0, 0, 0};
    }
    ps[rl][seg] = s; pss[rl][seg] = ss;
    __syncthreads();
    if (tid < 32) {
        float a = 0.f, b2 = 0.f;
#pragma unroll
        for (int j = 0; j < 8; j++) { a += ps[tid][j]; b2 += pss[tid][j]; }
        float mu = a * (1.f / DIM);
        float var = b2 * (1.f / DIM) - mu * mu;
        mu_s[tid] = mu;
        inv_s[tid] = rsqrtf(var + 1e-5f);
    }
    __syncthreads();
    if (ok) {
        float mu = mu_s[rl], inv = inv_s[rl];
        const float4* xp = (const float4*)(x + (size_t)row * DIM + seg * 32);
#pragma unroll
        for (int j = 0; j < 8; j++) {
            float4 xv = xp[j];
            int c = seg * 32 + j * 4;
            T[c + 0][rl] = xv.x + (yv[j].x - mu) * inv * g[c + 0] + bt[c + 0];
            T[c + 1][rl] = xv.y + (yv[j].y - mu) * inv * g[c + 1] + bt[c + 1];
            T[c + 2][rl] = xv.z + (yv[j].z - mu) * inv * g[c + 2] + bt[c + 2];
            T[c + 3][rl] = xv.w + (yv[j].w - mu) * inv * g[c + 3] + bt[c + 3];
        }
    }
    __syncthreads();
    const int w = tid >> 6, lane = tid & 63;
    const int hl = lane & 31, ch = lane >> 5;
    const int rr = r0 + hl;
    if (rr < 5000) {
        int b = rr / 2500, hw = rr % 2500;
        size_t obase = (size_t)b * 640000 + hw;
#pragma unroll
        for (int it = 0; it < 32; it++) {
            int c = it * 8 + w * 2 + ch;
            out[obase + (size_t)c * 2500] = T[c][hl];
        }
    }
}

// ---------------------------------------------------------------------------
extern "C" void kernel_launch(void* const* d_in, const int* in_sizes, int n_in,
                              void* d_out, int out_size, void* d_ws, size_t ws_size,
                              hipStream_t stream)
{
    const float* q     = (const float*)d_in[0];
    const float* k     = (const float*)d_in[1];
    const float* v     = (const float*)d_in[2];
    const float* Wq    = (const float*)d_in[3];
    const float* bq    = (const float*)d_in[4];
    const float* Wk    = (const float*)d_in[5];
    const float* bk    = (const float*)d_in[6];
    const float* Wv    = (const float*)d_in[7];
    const float* bv    = (const float*)d_in[8];
    const float* Wproj = (const float*)d_in[9];
    const float* bproj = (const float*)d_in[10];
    const float* Waddq = (const float*)d_in[11];
    const float* baddq = (const float*)d_in[12];
    const float* W1    = (const float*)d_in[13];
    const float* b1    = (const float*)d_in[14];
    const float* W2    = (const float*)d_in[15];
    const float* b2    = (const float*)d_in[16];
    const float* g_pre = (const float*)d_in[17];
    const float* b_pre = (const float*)d_in[18];
    const float* g_nrm = (const float*)d_in[19];
    const float* b_nrm = (const float*)d_in[20];
    float* out = (float*)d_out;

    // workspace layout (float-unit offsets)
    float* ws = (float*)d_ws;
    short* qf_a   = (short*)(ws);             // [0, 3.84M)
    short* lnbf   = (short*)(ws);             //   alias after attn
    short* qbf    = (short*)(ws + 3840000);   // [3.84M, 7.68M)
    short* kf_a   = (short*)(ws + 7680000);   // [7.68M, 8.64M)
    short* kpbf   = (short*)(ws + 8640000);   // [8.64M, 9.6M)
    short* vf_a   = (short*)(ws + 9600000);   // [9.6M, 10.56M)
    short* vpbf   = (short*)(ws + 10560000);  // [10.56M, 11.52M)
    float* add_q  = ws + 11520000;            // [11.52M, 12.8M)
    short* attn_o = (short*)(ws + 12800000);  // bf16: [12.8M, 16.64M)
    short* xbf    = (short*)(ws + 12800000);  //   alias: live only after ln_pre
    short* h1bf   = (short*)(ws + 13440000);  //   alias: [13.44M, 14.72M)
    float* add_q2 = ws + 16640000;            // [16.64M, 17.92M) split-K partial
    float* x      = ws + 20480000;            // [20.48M, 21.76M)
    float* Zp     = ws + 21760000;            // [21.76M, 22M)
    short* eW     = (short*)(ws + 22000000);
    short* Wq_t    = eW;
    short* Wk_t    = eW + 65536;
    short* Wv_t    = eW + 131072;
    short* Waddq_t = eW + 196608;
    short* lW     = (short*)(ws + 22295000);
    short* Wproj_t = lW;
    short* W1_t    = lW + 393216;
    short* W2_t    = lW + 524288;
    float* y2     = ws + 22625000;            // [22.62M, 23.9M)

    dim3 blk(256);

    // 1) all conversion work in one launch
    {
        WArgs wa;
        wa.j[0] = {Wq,    Wq_t,    256,  256};
        wa.j[1] = {Wk,    Wk_t,    256,  256};
        wa.j[2] = {Wv,    Wv_t,    256,  256};
        wa.j[3] = {Waddq, Waddq_t, 1536, 256};
        wa.j[4] = {Wproj, Wproj_t, 1536, 256};
        wa.j[5] = {W1,    W1_t,    256,  512};
        wa.j[6] = {W2,    W2_t,    512,  256};
        prep_all<<<dim3(12640), blk, 0, stream>>>(q, k, v, qbf, kpbf, vpbf, wa);
    }
    // 2) all input-side GEMMs, flat grid: long add_q blocks first (HW
    //    round-robin spreads them across XCDs) + split-K(2x768)
    //    qf job pre-scales by softmax scale * log2e (consumed only by attn)
    {
        GArgs ga;
        //          A     Bt       bias     Cb       Cf      M      Ks    Kl   kOff mode smul
        ga.j[0] = {qbf,  Waddq_t, baddq,   nullptr, add_q,  5000,  1536, 768, 0,   1, 1.0f};
        ga.j[1] = {qbf,  Waddq_t, nullptr, nullptr, add_q2, 5000,  1536, 768, 768, 1, 1.0f};
        ga.j[2] = {qbf,  Wq_t,    bq,      qf_a,    nullptr, 30000, 256, 256, 0,   0, SCALE_LOG2E};
        ga.j[3] = {kpbf, Wk_t,    bk,      kf_a,    nullptr, 7500,  256, 256, 0,   0, 1.0f};
        ga.j[4] = {vpbf, Wv_t,    bv,      vf_a,    nullptr, 7500,  256, 256, 0,   0, 1.0f};
        int cnt[5] = {160, 160, 940, 236, 236};   // 40*4, 40*4, 235*4, 59*4, 59*4
        ga.base[0] = 0;
        for (int i = 0; i < 5; i++) ga.base[i + 1] = ga.base[i] + cnt[i];
        gemm_in<<<dim3(ga.base[5]), blk, 0, stream>>>(ga);
    }
    // 3) attention (TQA=128: two q-groups share each staged K/V chunk)
    attn_mfma<<<dim3(20, 16, 6), blk, 0, stream>>>(qf_a, kf_a, vf_a, attn_o, Zp);
    // 4) LN(1536) + softmax-normalize -> bf16 (into dead qf_a region)
    ln_pre_kernel<<<dim3(5000), blk, 0, stream>>>(attn_o, lnbf, Zp, g_pre, b_pre);
    // 5) x = ln @ Wproj + bproj + add_q + add_q2  (fp32 x + bf16 xbf), BM=64
    mgemm64<2, 1, 1><<<dim3(4, 79), blk, 0, stream>>>(
        lnbf, Wproj_t, bproj, add_q, add_q2, x, xbf, 5000, 256, 1536);
    // 6) h1 = gelu(x @ W1 + b1) -> bf16, BM=64
    mgemm64<1, 0, 1><<<dim3(8, 79), blk, 0, stream>>>(
        xbf, W1_t, b1, nullptr, nullptr, nullptr, h1bf, 5000, 512, 256);
    // 7) y2 = h1 @ W2 + b2 -> fp32, BM=64
    mgemm64<0, 1, 0><<<dim3(4, 79), blk, 0, stream>>>(
        h1bf, W2_t, b2, nullptr, nullptr, y2, nullptr, 5000, 256, 512);
    // 8) out = transpose(x + LN256(y2)) — coalesced
    final_kernel2<<<dim3(157), blk, 0, stream>>>(x, y2, g_nrm, b_nrm, out);
}